// Round 10
// baseline (2386.373 us; speedup 1.0000x reference)
//
#include <hip/hip_runtime.h>

typedef unsigned long long u64;
typedef unsigned int u32;
typedef unsigned short ushort_t;

#define HH 200
#define WW 200
#define HWP 40000          // 200*200 pixels
#define NANCH 360000       // HWP * 9
#define PRE 6000
#define POST 300
#define NW 94              // 64-bit mask words per NMS row (ceil(6000/64))
#define NBINS 16384
#define KCAP 8192
#define CS 40              // halo cell stride in ushorts (80B): 16B-aligned

typedef __attribute__((ext_vector_type(8))) _Float16 f16x8;
typedef __attribute__((ext_vector_type(4))) float f32x4;

// ---------------- workspace layout (unchanged footprint) ----
static constexpr size_t X_F    = 0;                          // conv1 output x[512][40000] (+64 slack)
static constexpr size_t X_CNT  = 512ULL*HWP + 64;
static constexpr size_t W1B_F  = X_F + X_CNT;                // packed B planes 1+2 (f16): 4.72M ushorts
static constexpr size_t WT64_F = W1B_F + 4608ULL*512;        // packed cls/loc weights [512][64]
static constexpr size_t B64_F  = WT64_F + 512ULL*64;         // packed bias [64]
static constexpr size_t SC_F   = B64_F + 64;                 // scores [360000]
static constexpr size_t ROI_F  = SC_F + NANCH;               // decoded boxes [360000][4]
static constexpr size_t BOX_F  = ROI_F + 4ULL*NANCH;         // top-6000 boxes (pad 6016) [4]
static constexpr size_t FEND_F = BOX_F + 6016ULL*4;
static constexpr size_t HIST_B = ((FEND_F*4 + 255)/256)*256; // u32[16384]
static constexpr size_t CTRL_B = HIST_B + NBINS*4;           // u32[64]: [0]=cnt, [1]=cutoff bucket
static constexpr size_t KEY_B  = CTRL_B + 256;               // u64[8192] candidate keys
static constexpr size_t SORT_B = KEY_B + (size_t)KCAP*8;     // u64[6016] sorted keys
static constexpr size_t VALW_B = SORT_B + 6016ULL*8;         // u64[94] validity bits
static constexpr size_t MASK_B = ((VALW_B + NW*8 + 255)/256)*256; // u64[6000][94] NMS mask
static constexpr size_t WS_END = MASK_B + (size_t)PRE*NW*8;  // ~103.5 MB total

// ---------------- helpers ----------------
__device__ __forceinline__ u32 fsort(float f) {
  u32 u = __float_as_uint(f);
  return (u & 0x80000000u) ? ~u : (u | 0x80000000u);
}
__device__ __forceinline__ int bucket_of(float s) {
  int b = (int)((s + 1.0f) * 8191.0f);
  return b < 0 ? 0 : (b > 16383 ? 16383 : b);
}
__device__ __forceinline__ ushort_t h_bits(_Float16 h) {
  union { _Float16 h; ushort_t u; } c; c.h = h; return c.u;
}
// f16x2 split of a float pair -> two packed u32 (plane1: h1, plane2: h2*2048)
__device__ __forceinline__ void split_pack(float fA, float fB, u32& w1, u32& w2) {
  _Float16 hA = (_Float16)fA, hB = (_Float16)fB;
  float rA = fA - (float)hA, rB = fB - (float)hB;
  _Float16 cA = (_Float16)(rA * 2048.0f), cB = (_Float16)(rB * 2048.0f);
  w1 = (u32)h_bits(hA) | ((u32)h_bits(hB) << 16);
  w2 = (u32)h_bits(cA) | ((u32)h_bits(cB) << 16);
}

// single-x halo load (one ci-pair): raw floats, no split
__device__ __forceinline__ void halo_load1(const float* __restrict__ fbn, int y, int y0, int x0,
                                           int x, float& a0, float& b0) {
  int gy = y0 + y - 1, gx = x0 + x - 1;
  bool ok = ((unsigned)gy < 200u) && ((unsigned)gx < 200u);
  int off = ok ? (gy*200 + gx) : 0;
  float fA = fbn[off], fB = fbn[off + HWP];
  a0 = ok ? fA : 0.f;  b0 = ok ? fB : 0.f;
}
// linear write (NO swizzle -- R8 measured: XOR swizzle RAISED conflicts 1.8x)
__device__ __forceinline__ void halo_write1(u32* __restrict__ H1u, u32* __restrict__ H2u,
                                            int y, int x, int cih, float a0, float b0) {
  u32 w1v, w2v;
  split_pack(a0, b0, w1v, w2v);
  int idx = (y*18 + x)*(CS/2) + cih;
  H1u[idx] = w1v;
  H2u[idx] = w2v;
}
// 2-row batches: only 4 floats live per batch per thread
template<int Y0>
__device__ __forceinline__ void halo_load2(const float* __restrict__ fbn, int y0, int x0,
                                           int x, float* sA, float* sB) {
  #pragma unroll
  for (int yy = 0; yy < 2; ++yy)
    halo_load1(fbn, Y0 + yy, y0, x0, x, sA[yy], sB[yy]);
}
template<int Y0>
__device__ __forceinline__ void halo_write2(u32* __restrict__ H1u, u32* __restrict__ H2u,
                                            int x, int cih, float* sA, float* sB) {
  #pragma unroll
  for (int yy = 0; yy < 2; ++yy)
    halo_write1(H1u, H2u, Y0 + yy, x, cih, sA[yy], sB[yy]);
}

// ---------------- K0a: prepack w1 -> 2 f16 planes (h1, h2*2048), TAP-MAJOR k-order ----
// step s = chunk*9 + tap (chunk = ci>>5), within-step k-index = ci&31.
// R10 grouping for 64-och blocks: zi = och>>6 (8 blocks), wnb = (och>>5)&1, j = (och>>4)&1.
// fragment: p12[(((zi*144+s)*2+wnb)*2+j)*1024 + p*512 + lane*8 + e]  (p in {0,1})
__global__ void pack_w1b(const float* __restrict__ w1, ushort_t* __restrict__ p12) {
  int idx = blockIdx.x*256 + threadIdx.x;
  if (idx >= 512*4608) return;
  int och = idx / 4608, k = idx - (idx/4608)*4608;   // k = ci*9 + tap (reference order)
  float f = w1[idx];
  _Float16 h1 = (_Float16)f;
  float r = f - (float)h1;
  _Float16 h2 = (_Float16)(r * 2048.0f);
  int ci = k / 9, tap = k - ci*9;
  int chunk = ci >> 5, cil = ci & 31;
  int s = chunk*9 + tap;
  int zi = och >> 6, oz = och & 63;
  int wnb = oz >> 5, j = (oz >> 4) & 1, lmm = oz & 15;
  int lg = cil >> 3, e = cil & 7;
  int lane = lg*16 + lmm;
  size_t base = (((size_t)zi*144 + s)*2 + wnb)*2 + j;
  p12[base*1024 +       lane*8 + e] = h_bits(h1);
  p12[base*1024 + 512 + lane*8 + e] = h_bits(h2);
}

// ---------------- K0b: pack wc(18)/wl(36) -> wt[ci][64] (zero-padded), bias[64] ----------------
__global__ void pack_wcl(const float* __restrict__ wc, const float* __restrict__ bc,
                         const float* __restrict__ wl, const float* __restrict__ bl,
                         float* __restrict__ wt, float* __restrict__ b64) {
  int idx = blockIdx.x*256 + threadIdx.x;
  if (idx < 512*64) {
    int ci = idx >> 6, o = idx & 63;
    float v = 0.f;
    if (o < 18) v = wc[o*512 + ci];
    else if (o < 54) v = wl[(o-18)*512 + ci];
    wt[idx] = v;
  } else if (idx < 512*64 + 64) {
    int o = idx - 512*64;
    float v = 0.f;
    if (o < 18) v = bc[o]; else if (o < 54) v = bl[o-18];
    b64[o] = v;
  }
}

// ---------------- K1: 3x3 conv 512->512 + ReLU, f16x2 split, halo-LDS tap-major ----------
// R10: OCCUPANCY restructure. Every config so far ran at ~20% occupancy because total
// regs/wave = ~128 arch + 64 acc = 192 -> 8 waves/CU (2/SIMD): every stall is only
// half-covered, which is why MFMA-busy (~259us) ~= the 284us floor yet wall time was
// 753us, and why R7/R8/R9's ILP tweaks all failed.
// Fix: block tile 128px x 64och (grid z 4->8), 8 waves as 4M x 2N, wave = 32px x 32och
// -> acc = 32 VGPRs. Live set ~95 <= 128 total (enforced by __launch_bounds__(512,4))
// -> 16 waves/CU = 4 waves/SIMD, 2 blocks/CU (LDS 2x57.9KB = 115.7 <= 160KB).
// Per-CU pipe demands unchanged vs R6 (2 half-blocks = same MFMA/LDS/B per tap);
// cost = 2x staging VALU + 2x logical feat reads (feat is L3-resident).
// Scheduling kept SIMPLE (R6 staging, direct fb loads): TLP now does the hiding.
__global__ __launch_bounds__(512, 4) void conv3x3_mfma(const float* __restrict__ feat,
    const ushort_t* __restrict__ p12,
    const float* __restrict__ b1, float* __restrict__ xout) {
  __shared__ ushort_t H1[2][10*18*CS], H2[2][10*18*CS];   // double-buffered halo, 57.6KB
  const int t = threadIdx.x;
  const int x0 = blockIdx.x*16, y0 = blockIdx.y*8;
  const int zi = blockIdx.z;               // 0..7 -> 64 och per block
  const int ob = zi*64;

  const int wave = t >> 6, lane = t & 63;
  const int wm = (wave & 3)*32;            // M quarter (32 pixels)
  const int wnb = wave >> 2;               // N half (32 och)
  const int lm = lane & 15, lg = lane >> 4;
  const int lyb = (wave & 3)*2;            // tile-row base of this wave's M
  const int fragoff = lm*CS + lg*8;        // per-lane ushort offset into a halo row

  // staging map: cih = t>>5 (ci pair 0..15), x-slot = t&31 (active if <18)
  const int cih = t >> 5;
  const int sxo = t & 31;
  const bool act = sxo < 18;

  f32x4 accM[2][2], accC[2][2];            // 32 VGPRs total
  #pragma unroll
  for (int i = 0; i < 2; ++i)
    #pragma unroll
    for (int j = 0; j < 2; ++j) {
      accM[i][j] = (f32x4){0.f, 0.f, 0.f, 0.f};
      accC[i][j] = (f32x4){0.f, 0.f, 0.f, 0.f};
    }

  float sA[2], sB[2];                      // one 2-row staging batch (4 floats)

  // ---- prologue: stage chunk 0 into buffer 0 (5 sequential 2-row batches) ----
  {
    const float* fbn = feat + (size_t)(2*cih)*HWP;
    u32* h1n = (u32*)H1[0];  u32* h2n = (u32*)H2[0];
    if (act) {
      halo_load2<0>(fbn, y0, x0, sxo, sA, sB);
      halo_write2<0>(h1n, h2n, sxo, cih, sA, sB);
      halo_load2<2>(fbn, y0, x0, sxo, sA, sB);
      halo_write2<2>(h1n, h2n, sxo, cih, sA, sB);
      halo_load2<4>(fbn, y0, x0, sxo, sA, sB);
      halo_write2<4>(h1n, h2n, sxo, cih, sA, sB);
      halo_load2<6>(fbn, y0, x0, sxo, sA, sB);
      halo_write2<6>(h1n, h2n, sxo, cih, sA, sB);
      halo_load2<8>(fbn, y0, x0, sxo, sA, sB);
      halo_write2<8>(h1n, h2n, sxo, cih, sA, sB);
    }
  }

  // per-wave B pointer: groups of 1024 ushorts; step advance = 4 groups = 4096
  const ushort_t* pb = p12 + (size_t)zi*589824 + (size_t)wnb*2048 + lane*8;

  for (int c = 0; c < 16; ++c) {
    __syncthreads();   // buf[c&1] ready; all reads of buf[(c+1)&1] (iter c-1) done
    const ushort_t* h1c = H1[c & 1];
    const ushort_t* h2c = H2[c & 1];
    u32* h1n = (u32*)H1[(c + 1) & 1];
    u32* h2n = (u32*)H2[(c + 1) & 1];
    const float* fbn = feat + (size_t)(2*cih)*HWP + (size_t)(c + 1)*32*HWP;
    const bool stg = act && (c < 15);

    #pragma unroll 1
    for (int tap = 0; tap < 9; ++tap) {
      const int dy = tap/3, dx = tap - (tap/3)*3;
      // ---- A fragments: 4 ds_read_b128 (linear layout), issued first ----
      f16x8 fa1[2], fa2[2];
      #pragma unroll
      for (int i = 0; i < 2; ++i) {
        int addr = (lyb + i + dy)*(18*CS) + dx*CS + fragoff;
        fa1[i] = *(const f16x8*)&h1c[addr];
        fa2[i] = *(const f16x8*)&h2c[addr];
      }
      // ---- T14 staging (R6 pattern): load batch @ tap k, write @ tap k+1 ----
      if (stg) {
        if (tap == 0) {
          halo_load2<0>(fbn, y0, x0, sxo, sA, sB);
        } else if (tap == 1) {
          halo_write2<0>(h1n, h2n, sxo, cih, sA, sB);
          halo_load2<2>(fbn, y0, x0, sxo, sA, sB);
        } else if (tap == 2) {
          halo_write2<2>(h1n, h2n, sxo, cih, sA, sB);
          halo_load2<4>(fbn, y0, x0, sxo, sA, sB);
        } else if (tap == 3) {
          halo_write2<4>(h1n, h2n, sxo, cih, sA, sB);
          halo_load2<6>(fbn, y0, x0, sxo, sA, sB);
        } else if (tap == 4) {
          halo_write2<6>(h1n, h2n, sxo, cih, sA, sB);
          halo_load2<8>(fbn, y0, x0, sxo, sA, sB);
        } else if (tap == 5) {
          halo_write2<8>(h1n, h2n, sxo, cih, sA, sB);
        }
      }
      // ---- 2 j-stages: direct fb loads + 6 MFMA each (TLP hides load latency) ----
      #pragma unroll
      for (int j = 0; j < 2; ++j) {
        f16x8 cb1 = *(const f16x8*)(pb + j*1024);
        f16x8 cb2 = *(const f16x8*)(pb + j*1024 + 512);
        #pragma unroll
        for (int i = 0; i < 2; ++i) {
          accM[i][j] = __builtin_amdgcn_mfma_f32_16x16x32_f16(fa1[i], cb1, accM[i][j], 0, 0, 0);
          accC[i][j] = __builtin_amdgcn_mfma_f32_16x16x32_f16(fa1[i], cb2, accC[i][j], 0, 0, 0);
          accC[i][j] = __builtin_amdgcn_mfma_f32_16x16x32_f16(fa2[i], cb1, accC[i][j], 0, 0, 0);
        }
      }
      pb += 4096;
    }
  }

  // epilogue: combine main + scaled cross, bias + relu, store x[och][pixel]
  #pragma unroll
  for (int i = 0; i < 2; ++i) {
    int prow = wm + i*16 + lg*4;
    #pragma unroll
    for (int j = 0; j < 2; ++j) {
      int o = ob + wnb*32 + j*16 + lm;
      float bias = b1[o];
      #pragma unroll
      for (int r = 0; r < 4; ++r) {
        int p  = prow + r;
        int yy = y0 + (p >> 4), xx = x0 + (p & 15);
        if (xx < WW) {
          float v = accM[i][j][r] + accC[i][j][r] * 4.8828125e-4f + bias; // 2^-11
          xout[(size_t)o*HWP + yy*200 + xx] = fmaxf(v, 0.f);
        }
      }
    }
  }
}

// ---------------- K2: 1x1 convs (cls+loc) as GEMM [40000 x 64] = x^T[40000x512] * wt[512x64] ----
__global__ __launch_bounds__(256, 4) void conv1x1(const float* __restrict__ x,
                                                  const float* __restrict__ wt,
                                                  const float* __restrict__ bias,
                                                  float* __restrict__ out) {
  __shared__ float Xs[16*128];
  __shared__ float Ws[16*64];
  const int t = threadIdx.x;
  const int m0 = blockIdx.x*128;
  float acc[32];
  #pragma unroll
  for (int i = 0; i < 32; ++i) acc[i] = 0.f;
  const int mb = t & 15, nb = t >> 4;
  const int mm = t & 127, hh = t >> 7;
  const int nn = t & 63,  h2 = t >> 6;

  for (int kb = 0; kb < 512; kb += 16) {
    #pragma unroll
    for (int j = 0; j < 8; ++j) {
      int kk = hh + 2*j;
      Xs[kk*128 + mm] = x[(size_t)(kb+kk)*HWP + m0 + mm];
    }
    #pragma unroll
    for (int j = 0; j < 4; ++j) {
      int kk = h2 + 4*j;
      Ws[kk*64 + nn] = wt[(size_t)(kb+kk)*64 + nn];
    }
    __syncthreads();
    #pragma unroll
    for (int kk = 0; kk < 16; ++kk) {
      float av[8], bv[4];
      *(float4*)&av[0] = *(const float4*)&Xs[kk*128 + mb*8];
      *(float4*)&av[4] = *(const float4*)&Xs[kk*128 + mb*8 + 4];
      *(float4*)&bv[0] = *(const float4*)&Ws[kk*64 + nb*4];
      #pragma unroll
      for (int i = 0; i < 8; ++i)
        #pragma unroll
        for (int jj = 0; jj < 4; ++jj)
          acc[i*4+jj] = fmaf(av[i], bv[jj], acc[i*4+jj]);
    }
    __syncthreads();
  }

  #pragma unroll
  for (int jj = 0; jj < 4; ++jj) {
    int o = nb*4 + jj;
    float bv = bias[o];
    #pragma unroll
    for (int i = 0; i < 8; ++i) {
      int mm2 = m0 + mb*8 + i;
      if (mm2 < HWP) {
        float v = acc[i*4+jj] + bv;
        if (o < 18)       out[(size_t)mm2*18 + o] = v;               // pred_cls: [m][2a+c]
        else if (o < 54)  out[720000 + (size_t)mm2*36 + (o-18)] = v; // pred_loc: [m][4a+j]
      }
    }
  }
}

// ---------------- K3: decode boxes + score + histogram ----------------
__global__ void decode(const float* __restrict__ dout, const float* __restrict__ anchor,
                       float* __restrict__ scores, float4* __restrict__ roi, u32* __restrict__ hist) {
  int n = blockIdx.x*256 + threadIdx.x;
  if (n >= NANCH) return;
  int mq = n / 9;
  int a  = n - mq*9;
  float c0 = dout[(size_t)mq*18 + 2*a];
  float c1 = dout[(size_t)mq*18 + 2*a + 1];
  float score = 1.0f / (1.0f + expf(c0 - c1));  // == softmax[:,1]; monotone in (c1-c0)
  const float* lp = dout + 720000 + (size_t)mq*36 + 4*a;
  float l0 = lp[0], l1 = lp[1], l2 = lp[2], l3 = lp[3];
  float4 an = ((const float4*)anchor)[n];
  float aw = an.z - an.x, ah = an.w - an.y;
  float acx = (an.x + an.z)*0.5f, acy = (an.y + an.w)*0.5f;
  float cx = l0*aw + acx, cy = l1*ah + acy;
  float bw = expf(l2)*aw, bh = expf(l3)*ah;
  float x1 = fminf(fmaxf(cx - bw*0.5f, 0.f), 1.f);
  float y1 = fminf(fmaxf(cy - bh*0.5f, 0.f), 1.f);
  float x2 = fminf(fmaxf(cx + bw*0.5f, 0.f), 1.f);
  float y2 = fminf(fmaxf(cy + bh*0.5f, 0.f), 1.f);
  bool valid = ((y2 - y1) >= 0.016f) && ((x2 - x1) >= 0.016f);
  float sc = valid ? score : -1.0f;
  scores[n] = sc;
  roi[n] = make_float4(x1, y1, x2, y2);
  atomicAdd(&hist[bucket_of(sc)], 1u);
}

// ---------------- K4: find cutoff bucket B ----------------
__global__ void scan_hist(const u32* __restrict__ hist, u32* __restrict__ ctrl) {
  __shared__ u32 seg[256];
  int t = threadIdx.x;
  u32 s = 0;
  for (int b = 0; b < 64; ++b) s += hist[t*64 + b];
  seg[t] = s;
  __syncthreads();
  if (t == 0) {
    u32 cum = 0; int B = 0;
    for (int sg = 255; sg >= 0; --sg) {
      if (cum + seg[sg] >= PRE) {
        for (int b = sg*64 + 63; b >= sg*64; --b) {
          cum += hist[b];
          if (cum >= PRE) { B = b; break; }
        }
        break;
      }
      cum += seg[sg];
    }
    ctrl[1] = (u32)B;
  }
}

// ---------------- K5: compact candidates (bucket >= B) into keybuf ----------------
__global__ void compact(const float* __restrict__ scores, u32* __restrict__ ctrl, u64* __restrict__ keybuf) {
  int n = blockIdx.x*256 + threadIdx.x;
  if (n >= NANCH) return;
  float s = scores[n];
  int B = (int)ctrl[1];
  if (bucket_of(s) >= B) {
    u32 pos = atomicAdd(&ctrl[0], 1u);
    if (pos < KCAP) {
      keybuf[pos] = ((u64)fsort(s) << 32) | (u64)(0xFFFFFFFFu - (u32)n); // ties: lower n wins
    }
  }
}

// ---------------- K6: single-block bitonic sort of 8192 u64 keys, descending ----------------
__global__ __launch_bounds__(1024) void sortk(const u64* __restrict__ keybuf, const u32* __restrict__ ctrl,
                                              u64* __restrict__ sorted) {
  __shared__ u64 s[KCAP];
  int t = threadIdx.x;
  u32 cnt = ctrl[0]; if (cnt > KCAP) cnt = KCAP;
  for (int i = t; i < KCAP; i += 1024) s[i] = (i < (int)cnt) ? keybuf[i] : 0ULL;
  __syncthreads();
  for (int size = 2; size <= KCAP; size <<= 1) {
    for (int stride = size >> 1; stride > 0; stride >>= 1) {
      for (int w = t; w < KCAP/2; w += 1024) {
        int lo = ((w & ~(stride-1)) << 1) | (w & (stride-1));
        int hi = lo + stride;
        bool desc = ((lo & size) == 0);
        u64 a = s[lo], b = s[hi];
        if ((a < b) == desc) { s[lo] = b; s[hi] = a; }
      }
      __syncthreads();
    }
  }
  for (int i = t; i < 6016; i += 1024) sorted[i] = s[i];
}

// ---------------- K6b: gather top-6000 boxes + validity bits ----------------
__global__ void gather_topk(const u64* __restrict__ sorted, const float4* __restrict__ roi,
                            float4* __restrict__ boxes, u64* __restrict__ validw) {
  int i = blockIdx.x*64 + threadIdx.x;
  bool valid = false;
  float4 b = make_float4(0.f, 0.f, 0.f, 0.f);
  if (i < PRE) {
    u64 k = sorted[i];
    if (k) {
      u32 n = 0xFFFFFFFFu - (u32)(k & 0xFFFFFFFFu);
      if (n < NANCH) { b = roi[n]; valid = (k >> 63) != 0; }
    }
  }
  boxes[i] = b;
  u64 bal = __ballot(valid);
  if (threadIdx.x == 0) validw[blockIdx.x] = bal;
}

// ---------------- K7: NMS suppression bitmask ----------------
__global__ void nms_mask(const float4* __restrict__ boxes, u64* __restrict__ mask) {
  int bi = blockIdx.y, bj = blockIdx.x;
  int t = threadIdx.x;
  int i = bi*64 + t;
  if (bj < bi) {
    if (i < PRE) mask[(size_t)i*NW + bj] = 0ULL;
    return;
  }
  __shared__ float4 cb[64];
  int j0 = bj*64;
  cb[t] = boxes[j0 + t];
  __syncthreads();
  if (i >= PRE) return;
  float4 b = boxes[i];
  float area_i = (b.z - b.x) * (b.w - b.y);
  u64 bits = 0;
  #pragma unroll 4
  for (int jj = 0; jj < 64; ++jj) {
    int j = j0 + jj;
    float4 c = cb[jj];
    float xx1 = fmaxf(b.x, c.x), yy1 = fmaxf(b.y, c.y);
    float xx2 = fminf(b.z, c.z), yy2 = fminf(b.w, c.w);
    float inter = fmaxf(xx2 - xx1, 0.f) * fmaxf(yy2 - yy1, 0.f);
    float area_j = (c.z - c.x) * (c.w - c.y);
    float iou = inter / (area_i + area_j - inter + 1e-12f);
    if (iou > 0.7f && j > i) bits |= (1ULL << jj);
  }
  mask[(size_t)i*NW + bj] = bits;
}

// ---------------- K8: sequential greedy scan + emit first 300 kept boxes ----------------
__global__ void nms_scan(const u64* __restrict__ mask, const u64* __restrict__ validw,
                         const float* __restrict__ boxes, float* __restrict__ rois) {
  int lane = threadIdx.x;
  u64 r0 = ~validw[lane];
  u64 r1 = (lane < NW-64) ? ~validw[64 + lane] : ~0ULL;
  int kept = 0;
  u64 m0 = mask[lane];
  u64 m1 = (lane < NW-64) ? mask[64 + lane] : 0ULL;
  for (int i = 0; i < PRE; ++i) {
    int wi = i >> 6;
    u64 w0 = __shfl(r0, wi & 63);
    u64 w1 = __shfl(r1, wi & 63);
    u64 wv = (wi < 64) ? w0 : w1;
    if (!((wv >> (i & 63)) & 1ULL)) {
      if (lane < 4) rois[kept*4 + lane] = boxes[(size_t)i*4 + lane];
      kept++;
      if (kept >= POST) break;
      r0 |= m0;
      if (lane < NW-64) r1 |= m1;
    }
    if (i + 1 < PRE) {
      m0 = mask[(size_t)(i+1)*NW + lane];
      m1 = (lane < NW-64) ? mask[(size_t)(i+1)*NW + 64 + lane] : 0ULL;
    }
  }
}

extern "C" void kernel_launch(void* const* d_in, const int* in_sizes, int n_in,
                              void* d_out, int out_size, void* d_ws, size_t ws_size,
                              hipStream_t stream) {
  const float* feat   = (const float*)d_in[0];
  const float* anchor = (const float*)d_in[1];
  const float* w1     = (const float*)d_in[2];
  const float* b1     = (const float*)d_in[3];
  const float* wc     = (const float*)d_in[4];
  const float* bc     = (const float*)d_in[5];
  const float* wl     = (const float*)d_in[6];
  const float* bl     = (const float*)d_in[7];
  float* out = (float*)d_out;
  char*  ws  = (char*)d_ws;
  float* wsf = (float*)d_ws;

  if (ws_size < WS_END) return;  // need ~103.5 MB

  float*    x      = wsf + X_F;
  ushort_t* p12    = (ushort_t*)(wsf + W1B_F);   // packed B planes 1+2 (f16, 9.44 MB)
  float*    wt64   = wsf + WT64_F;
  float*    b64    = wsf + B64_F;
  float*    scores = wsf + SC_F;
  float4*   roi    = (float4*)(wsf + ROI_F);
  float4*   boxes  = (float4*)(wsf + BOX_F);
  u32* hist   = (u32*)(ws + HIST_B);
  u32* ctrl   = (u32*)(ws + CTRL_B);
  u64* keybuf = (u64*)(ws + KEY_B);
  u64* sorted = (u64*)(ws + SORT_B);
  u64* validw = (u64*)(ws + VALW_B);
  u64* mask   = (u64*)(ws + MASK_B);

  hipMemsetAsync(ws + HIST_B, 0, NBINS*4 + 256, stream);
  hipMemsetAsync(out + 2160000, 0, POST*4*sizeof(float), stream);

  pack_w1b<<<9216, 256, 0, stream>>>(w1, p12);
  pack_wcl<<<129, 256, 0, stream>>>(wc, bc, wl, bl, wt64, b64);
  conv3x3_mfma<<<dim3(13, 25, 8), 512, 0, stream>>>(feat, p12, b1, x);
  conv1x1<<<313, 256, 0, stream>>>(x, wt64, b64, out);
  decode<<<1407, 256, 0, stream>>>(out, anchor, scores, roi, hist);
  scan_hist<<<1, 256, 0, stream>>>(hist, ctrl);
  compact<<<1407, 256, 0, stream>>>(scores, ctrl, keybuf);
  sortk<<<1, 1024, 0, stream>>>(keybuf, ctrl, sorted);
  gather_topk<<<NW, 64, 0, stream>>>(sorted, roi, boxes, validw);
  nms_mask<<<dim3(NW, NW), 64, 0, stream>>>(boxes, mask);
  nms_scan<<<1, 64, 0, stream>>>(mask, validw, (const float*)boxes, out + 2160000);
}

// Round 11
// 1402.928 us; speedup vs baseline: 1.7010x; 1.7010x over previous
//
#include <hip/hip_runtime.h>

typedef unsigned long long u64;
typedef unsigned int u32;
typedef unsigned short ushort_t;

#define HH 200
#define WW 200
#define HWP 40000          // 200*200 pixels
#define NANCH 360000       // HWP * 9
#define PRE 6000
#define POST 300
#define NW 94              // 64-bit mask words per NMS row (ceil(6000/64))
#define NBINS 16384
#define KCAP 8192
#define CS 40              // halo cell stride in ushorts (80B): 16B-aligned

typedef __attribute__((ext_vector_type(8))) _Float16 f16x8;
typedef __attribute__((ext_vector_type(4))) float f32x4;

// ---------------- workspace layout (unchanged footprint) ----
static constexpr size_t X_F    = 0;                          // conv1 output x[512][40000] (+64 slack)
static constexpr size_t X_CNT  = 512ULL*HWP + 64;
static constexpr size_t W1B_F  = X_F + X_CNT;                // packed B planes 1+2 (f16): 4.72M ushorts
static constexpr size_t WT64_F = W1B_F + 4608ULL*512;        // packed cls/loc weights [512][64]
static constexpr size_t B64_F  = WT64_F + 512ULL*64;         // packed bias [64]
static constexpr size_t SC_F   = B64_F + 64;                 // scores [360000]
static constexpr size_t ROI_F  = SC_F + NANCH;               // decoded boxes [360000][4]
static constexpr size_t BOX_F  = ROI_F + 4ULL*NANCH;         // top-6000 boxes (pad 6016) [4]
static constexpr size_t FEND_F = BOX_F + 6016ULL*4;
static constexpr size_t HIST_B = ((FEND_F*4 + 255)/256)*256; // u32[16384]
static constexpr size_t CTRL_B = HIST_B + NBINS*4;           // u32[64]: [0]=cnt, [1]=cutoff bucket
static constexpr size_t KEY_B  = CTRL_B + 256;               // u64[8192] candidate keys
static constexpr size_t SORT_B = KEY_B + (size_t)KCAP*8;     // u64[6016] sorted keys
static constexpr size_t VALW_B = SORT_B + 6016ULL*8;         // u64[94] validity bits
static constexpr size_t MASK_B = ((VALW_B + NW*8 + 255)/256)*256; // u64[6000][94] NMS mask
static constexpr size_t WS_END = MASK_B + (size_t)PRE*NW*8;  // ~103.5 MB total

// ---------------- helpers ----------------
__device__ __forceinline__ u32 fsort(float f) {
  u32 u = __float_as_uint(f);
  return (u & 0x80000000u) ? ~u : (u | 0x80000000u);
}
__device__ __forceinline__ int bucket_of(float s) {
  int b = (int)((s + 1.0f) * 8191.0f);
  return b < 0 ? 0 : (b > 16383 ? 16383 : b);
}
__device__ __forceinline__ ushort_t h_bits(_Float16 h) {
  union { _Float16 h; ushort_t u; } c; c.h = h; return c.u;
}
// f16x2 split of a float pair -> two packed u32 (plane1: h1, plane2: h2*2048)
__device__ __forceinline__ void split_pack(float fA, float fB, u32& w1, u32& w2) {
  _Float16 hA = (_Float16)fA, hB = (_Float16)fB;
  float rA = fA - (float)hA, rB = fB - (float)hB;
  _Float16 cA = (_Float16)(rA * 2048.0f), cB = (_Float16)(rB * 2048.0f);
  w1 = (u32)h_bits(hA) | ((u32)h_bits(hB) << 16);
  w2 = (u32)h_bits(cA) | ((u32)h_bits(cB) << 16);
}

// single-x halo load (one ci-pair): raw floats, no split
__device__ __forceinline__ void halo_load1(const float* __restrict__ fbn, int y, int y0, int x0,
                                           int x, float& a0, float& b0) {
  int gy = y0 + y - 1, gx = x0 + x - 1;
  bool ok = ((unsigned)gy < 200u) && ((unsigned)gx < 200u);
  int off = ok ? (gy*200 + gx) : 0;
  float fA = fbn[off], fB = fbn[off + HWP];
  a0 = ok ? fA : 0.f;  b0 = ok ? fB : 0.f;
}
// linear write (NO swizzle -- R8 measured: XOR swizzle RAISED conflicts 1.8x)
__device__ __forceinline__ void halo_write1(u32* __restrict__ H1u, u32* __restrict__ H2u,
                                            int y, int x, int cih, float a0, float b0) {
  u32 w1v, w2v;
  split_pack(a0, b0, w1v, w2v);
  int idx = (y*18 + x)*(CS/2) + cih;
  H1u[idx] = w1v;
  H2u[idx] = w2v;
}
// 2-row batches: only 4 floats live per batch per thread
template<int Y0>
__device__ __forceinline__ void halo_load2(const float* __restrict__ fbn, int y0, int x0,
                                           int x, float* sA, float* sB) {
  #pragma unroll
  for (int yy = 0; yy < 2; ++yy)
    halo_load1(fbn, Y0 + yy, y0, x0, x, sA[yy], sB[yy]);
}
template<int Y0>
__device__ __forceinline__ void halo_write2(u32* __restrict__ H1u, u32* __restrict__ H2u,
                                            int x, int cih, float* sA, float* sB) {
  #pragma unroll
  for (int yy = 0; yy < 2; ++yy)
    halo_write1(H1u, H2u, Y0 + yy, x, cih, sA[yy], sB[yy]);
}

// ---------------- K0a: prepack w1 -> 2 f16 planes (h1, h2*2048), TAP-MAJOR k-order ----
// step s = chunk*9 + tap (chunk = ci>>5), within-step k-index = ci&31.
// Grouping (= R6, harness-verified at 753us): wnb = oz>>5 (4 groups of 32 och),
// j = (oz>>4)&1. fragment: p12[(((z*144+s)*4+wnb)*2+j)*1024 + p*512 + lane*8 + e]
__global__ void pack_w1b(const float* __restrict__ w1, ushort_t* __restrict__ p12) {
  int idx = blockIdx.x*256 + threadIdx.x;
  if (idx >= 512*4608) return;
  int och = idx / 4608, k = idx - (idx/4608)*4608;   // k = ci*9 + tap (reference order)
  float f = w1[idx];
  _Float16 h1 = (_Float16)f;
  float r = f - (float)h1;
  _Float16 h2 = (_Float16)(r * 2048.0f);
  int ci = k / 9, tap = k - ci*9;
  int chunk = ci >> 5, cil = ci & 31;
  int s = chunk*9 + tap;
  int z = och >> 7, oz = och & 127;
  int wnb = oz >> 5, j = (oz >> 4) & 1, lmm = oz & 15;
  int lg = cil >> 3, e = cil & 7;
  int lane = lg*16 + lmm;
  size_t base = (((size_t)z*144 + s)*4 + wnb)*2 + j;
  p12[base*1024 +       lane*8 + e] = h_bits(h1);
  p12[base*1024 + 512 + lane*8 + e] = h_bits(h2);
}

// ---------------- K0b: pack wc(18)/wl(36) -> wt[ci][64] (zero-padded), bias[64] ----------------
__global__ void pack_wcl(const float* __restrict__ wc, const float* __restrict__ bc,
                         const float* __restrict__ wl, const float* __restrict__ bl,
                         float* __restrict__ wt, float* __restrict__ b64) {
  int idx = blockIdx.x*256 + threadIdx.x;
  if (idx < 512*64) {
    int ci = idx >> 6, o = idx & 63;
    float v = 0.f;
    if (o < 18) v = wc[o*512 + ci];
    else if (o < 54) v = wl[(o-18)*512 + ci];
    wt[idx] = v;
  } else if (idx < 512*64 + 64) {
    int o = idx - 512*64;
    float v = 0.f;
    if (o < 18) v = bc[o]; else if (o < 54) v = bl[o-18];
    b64[o] = v;
  }
}

// ---------------- K1: 3x3 conv 512->512 + ReLU, f16x2 split, halo-LDS tap-major ----------
// R11 = R6 exact (753us verified) + WAVE-PHASE ROTATION.
// R6 counter accounting: per CU per chunk-tap, wall = 2160cy = MFMA demand (932cy/SIMD)
// + LDS demand (~1190cy/CU) -- the pipes SERIALIZE because both waves on a SIMD run the
// identical tap sequence in barrier-locked phase: both burst ds_reads (MFMA idle), then
// both MFMA (LDS idle). This also explains why R7/R8/R9's within-wave ILP tweaks all
// failed: the waves stayed in phase.
// Fix: taps within a chunk are order-independent (each accumulates A(tap)*B(tap) into
// the same acc), so wave w processes taps in rotated order tap=(it+w)%9. Any two waves
// sharing a SIMD are >=1 tap (~590cy) out of phase: one reads while the other MFMAs.
// Cost: +2 ints; no barrier/numerics/layout changes (fp sum-order shift ~1e-6 only).
// Staging stays keyed on iteration index 'it' (R6 schedule). fb 1-ahead prefetch kept,
// pointer computed per-iteration from the rotated step sequence.
__global__ __launch_bounds__(512, 2) void conv3x3_mfma(const float* __restrict__ feat,
    const ushort_t* __restrict__ p12,
    const float* __restrict__ b1, float* __restrict__ xout) {
  __shared__ ushort_t H1[2][10*18*CS], H2[2][10*18*CS];   // double-buffered halo, 57.6KB
  const int t = threadIdx.x;
  const int x0 = blockIdx.x*16, y0 = blockIdx.y*8;
  const int zi = blockIdx.z;
  const int ob = zi*128;

  const int wave = t >> 6, lane = t & 63;
  const int wm = (wave & 1)*64;            // M half (64 pixels)
  const int wnb = wave >> 1;               // N quarter (32 och)
  const int lm = lane & 15, lg = lane >> 4;
  const int lyb = (wave & 1)*4;            // tile-row base of this wave's M
  const int fragoff = lm*CS + lg*8;        // per-lane ushort offset into a halo row
  const int off = wave;                    // per-wave tap-phase rotation (0..7)

  // staging map: cih = t>>5 (ci pair 0..15), x-slot = t&31 (active if <18)
  const int cih = t >> 5;
  const int sxo = t & 31;
  const bool act = sxo < 18;

  f32x4 accM[4][2], accC[4][2];
  #pragma unroll
  for (int i = 0; i < 4; ++i)
    #pragma unroll
    for (int j = 0; j < 2; ++j) {
      accM[i][j] = (f32x4){0.f, 0.f, 0.f, 0.f};
      accC[i][j] = (f32x4){0.f, 0.f, 0.f, 0.f};
    }

  float sA[2], sB[2];                      // one 2-row staging batch (4 floats)

  // ---- prologue: stage chunk 0 into buffer 0 (5 sequential 2-row batches) ----
  {
    const float* fbn = feat + (size_t)(2*cih)*HWP;
    u32* h1n = (u32*)H1[0];  u32* h2n = (u32*)H2[0];
    if (act) {
      halo_load2<0>(fbn, y0, x0, sxo, sA, sB);
      halo_write2<0>(h1n, h2n, sxo, cih, sA, sB);
      halo_load2<2>(fbn, y0, x0, sxo, sA, sB);
      halo_write2<2>(h1n, h2n, sxo, cih, sA, sB);
      halo_load2<4>(fbn, y0, x0, sxo, sA, sB);
      halo_write2<4>(h1n, h2n, sxo, cih, sA, sB);
      halo_load2<6>(fbn, y0, x0, sxo, sA, sB);
      halo_write2<6>(h1n, h2n, sxo, cih, sA, sB);
      halo_load2<8>(fbn, y0, x0, sxo, sA, sB);
      halo_write2<8>(h1n, h2n, sxo, cih, sA, sB);
    }
  }

  // per-wave B base; step s fragment block = pB + s*8192 (+ j*1024, + plane*512)
  const ushort_t* pB = p12 + (size_t)zi*1179648 + (size_t)wnb*2048 + lane*8;

  // ---- preload fb pair for this wave's first step: (c=0, it=0) -> tap=off ----
  f16x8 nb1 = *(const f16x8*)(pB + (size_t)off*8192);
  f16x8 nb2 = *(const f16x8*)(pB + (size_t)off*8192 + 512);

  for (int c = 0; c < 16; ++c) {
    __syncthreads();   // buf[c&1] ready; all reads of buf[(c+1)&1] (iter c-1) done
    const ushort_t* h1c = H1[c & 1];
    const ushort_t* h2c = H2[c & 1];
    u32* h1n = (u32*)H1[(c + 1) & 1];
    u32* h2n = (u32*)H2[(c + 1) & 1];
    const float* fbn = feat + (size_t)(2*cih)*HWP + (size_t)(c + 1)*32*HWP;
    const bool stg = act && (c < 15);

    #pragma unroll 1
    for (int it = 0; it < 9; ++it) {
      int tap = it + off; if (tap >= 9) tap -= 9;       // rotated tap for this wave
      const int dy = tap/3, dx = tap - (tap/3)*3;
      // ---- A fragments: 8 ds_read_b128 (linear layout), issued first ----
      f16x8 fa1[4], fa2[4];
      #pragma unroll
      for (int i = 0; i < 4; ++i) {
        int addr = (lyb + i + dy)*(18*CS) + dx*CS + fragoff;
        fa1[i] = *(const f16x8*)&h1c[addr];
        fa2[i] = *(const f16x8*)&h2c[addr];
      }
      // ---- T14 staging (R6 schedule, keyed on 'it'): load @ k, write @ k+1 ----
      if (stg) {
        if (it == 0) {
          halo_load2<0>(fbn, y0, x0, sxo, sA, sB);
        } else if (it == 1) {
          halo_write2<0>(h1n, h2n, sxo, cih, sA, sB);
          halo_load2<2>(fbn, y0, x0, sxo, sA, sB);
        } else if (it == 2) {
          halo_write2<2>(h1n, h2n, sxo, cih, sA, sB);
          halo_load2<4>(fbn, y0, x0, sxo, sA, sB);
        } else if (it == 3) {
          halo_write2<4>(h1n, h2n, sxo, cih, sA, sB);
          halo_load2<6>(fbn, y0, x0, sxo, sA, sB);
        } else if (it == 4) {
          halo_write2<6>(h1n, h2n, sxo, cih, sA, sB);
          halo_load2<8>(fbn, y0, x0, sxo, sA, sB);
        } else if (it == 5) {
          halo_write2<8>(h1n, h2n, sxo, cih, sA, sB);
        }
      }
      // ---- next step's fragment base (rotated sequence; wrap at very end is a
      //      harmless redundant reload, same as R6's lastS handling) ----
      int s_next;
      if (it < 8) {
        int tn = tap + 1; if (tn >= 9) tn -= 9;
        s_next = c*9 + tn;
      } else {
        s_next = (c < 15) ? (c + 1)*9 + off : off;
      }
      const ushort_t* pbs = pB + (size_t)(c*9 + tap)*8192;
      const ushort_t* pbn = pB + (size_t)s_next*8192;
      // ---- 2 j-stages of {consume prefetched pair; prefetch next; 12 MFMA} ----
      #pragma unroll
      for (int j = 0; j < 2; ++j) {
        f16x8 cb1 = nb1, cb2 = nb2;
        const ushort_t* nx = (j == 0) ? (pbs + 1024) : pbn;
        nb1 = *(const f16x8*)nx;
        nb2 = *(const f16x8*)(nx + 512);
        #pragma unroll
        for (int i = 0; i < 4; ++i) {
          accM[i][j] = __builtin_amdgcn_mfma_f32_16x16x32_f16(fa1[i], cb1, accM[i][j], 0, 0, 0);
          accC[i][j] = __builtin_amdgcn_mfma_f32_16x16x32_f16(fa1[i], cb2, accC[i][j], 0, 0, 0);
          accC[i][j] = __builtin_amdgcn_mfma_f32_16x16x32_f16(fa2[i], cb1, accC[i][j], 0, 0, 0);
        }
      }
    }
  }

  // epilogue: combine main + scaled cross, bias + relu, store x[och][pixel]
  #pragma unroll
  for (int i = 0; i < 4; ++i) {
    int prow = wm + i*16 + lg*4;
    #pragma unroll
    for (int j = 0; j < 2; ++j) {
      int o = ob + wnb*32 + j*16 + lm;
      float bias = b1[o];
      #pragma unroll
      for (int r = 0; r < 4; ++r) {
        int p  = prow + r;
        int yy = y0 + (p >> 4), xx = x0 + (p & 15);
        if (xx < WW) {
          float v = accM[i][j][r] + accC[i][j][r] * 4.8828125e-4f + bias; // 2^-11
          xout[(size_t)o*HWP + yy*200 + xx] = fmaxf(v, 0.f);
        }
      }
    }
  }
}

// ---------------- K2: 1x1 convs (cls+loc) as GEMM [40000 x 64] = x^T[40000x512] * wt[512x64] ----
__global__ __launch_bounds__(256, 4) void conv1x1(const float* __restrict__ x,
                                                  const float* __restrict__ wt,
                                                  const float* __restrict__ bias,
                                                  float* __restrict__ out) {
  __shared__ float Xs[16*128];
  __shared__ float Ws[16*64];
  const int t = threadIdx.x;
  const int m0 = blockIdx.x*128;
  float acc[32];
  #pragma unroll
  for (int i = 0; i < 32; ++i) acc[i] = 0.f;
  const int mb = t & 15, nb = t >> 4;
  const int mm = t & 127, hh = t >> 7;
  const int nn = t & 63,  h2 = t >> 6;

  for (int kb = 0; kb < 512; kb += 16) {
    #pragma unroll
    for (int j = 0; j < 8; ++j) {
      int kk = hh + 2*j;
      Xs[kk*128 + mm] = x[(size_t)(kb+kk)*HWP + m0 + mm];
    }
    #pragma unroll
    for (int j = 0; j < 4; ++j) {
      int kk = h2 + 4*j;
      Ws[kk*64 + nn] = wt[(size_t)(kb+kk)*64 + nn];
    }
    __syncthreads();
    #pragma unroll
    for (int kk = 0; kk < 16; ++kk) {
      float av[8], bv[4];
      *(float4*)&av[0] = *(const float4*)&Xs[kk*128 + mb*8];
      *(float4*)&av[4] = *(const float4*)&Xs[kk*128 + mb*8 + 4];
      *(float4*)&bv[0] = *(const float4*)&Ws[kk*64 + nb*4];
      #pragma unroll
      for (int i = 0; i < 8; ++i)
        #pragma unroll
        for (int jj = 0; jj < 4; ++jj)
          acc[i*4+jj] = fmaf(av[i], bv[jj], acc[i*4+jj]);
    }
    __syncthreads();
  }

  #pragma unroll
  for (int jj = 0; jj < 4; ++jj) {
    int o = nb*4 + jj;
    float bv = bias[o];
    #pragma unroll
    for (int i = 0; i < 8; ++i) {
      int mm2 = m0 + mb*8 + i;
      if (mm2 < HWP) {
        float v = acc[i*4+jj] + bv;
        if (o < 18)       out[(size_t)mm2*18 + o] = v;               // pred_cls: [m][2a+c]
        else if (o < 54)  out[720000 + (size_t)mm2*36 + (o-18)] = v; // pred_loc: [m][4a+j]
      }
    }
  }
}

// ---------------- K3: decode boxes + score + histogram ----------------
__global__ void decode(const float* __restrict__ dout, const float* __restrict__ anchor,
                       float* __restrict__ scores, float4* __restrict__ roi, u32* __restrict__ hist) {
  int n = blockIdx.x*256 + threadIdx.x;
  if (n >= NANCH) return;
  int mq = n / 9;
  int a  = n - mq*9;
  float c0 = dout[(size_t)mq*18 + 2*a];
  float c1 = dout[(size_t)mq*18 + 2*a + 1];
  float score = 1.0f / (1.0f + expf(c0 - c1));  // == softmax[:,1]; monotone in (c1-c0)
  const float* lp = dout + 720000 + (size_t)mq*36 + 4*a;
  float l0 = lp[0], l1 = lp[1], l2 = lp[2], l3 = lp[3];
  float4 an = ((const float4*)anchor)[n];
  float aw = an.z - an.x, ah = an.w - an.y;
  float acx = (an.x + an.z)*0.5f, acy = (an.y + an.w)*0.5f;
  float cx = l0*aw + acx, cy = l1*ah + acy;
  float bw = expf(l2)*aw, bh = expf(l3)*ah;
  float x1 = fminf(fmaxf(cx - bw*0.5f, 0.f), 1.f);
  float y1 = fminf(fmaxf(cy - bh*0.5f, 0.f), 1.f);
  float x2 = fminf(fmaxf(cx + bw*0.5f, 0.f), 1.f);
  float y2 = fminf(fmaxf(cy + bh*0.5f, 0.f), 1.f);
  bool valid = ((y2 - y1) >= 0.016f) && ((x2 - x1) >= 0.016f);
  float sc = valid ? score : -1.0f;
  scores[n] = sc;
  roi[n] = make_float4(x1, y1, x2, y2);
  atomicAdd(&hist[bucket_of(sc)], 1u);
}

// ---------------- K4: find cutoff bucket B ----------------
__global__ void scan_hist(const u32* __restrict__ hist, u32* __restrict__ ctrl) {
  __shared__ u32 seg[256];
  int t = threadIdx.x;
  u32 s = 0;
  for (int b = 0; b < 64; ++b) s += hist[t*64 + b];
  seg[t] = s;
  __syncthreads();
  if (t == 0) {
    u32 cum = 0; int B = 0;
    for (int sg = 255; sg >= 0; --sg) {
      if (cum + seg[sg] >= PRE) {
        for (int b = sg*64 + 63; b >= sg*64; --b) {
          cum += hist[b];
          if (cum >= PRE) { B = b; break; }
        }
        break;
      }
      cum += seg[sg];
    }
    ctrl[1] = (u32)B;
  }
}

// ---------------- K5: compact candidates (bucket >= B) into keybuf ----------------
__global__ void compact(const float* __restrict__ scores, u32* __restrict__ ctrl, u64* __restrict__ keybuf) {
  int n = blockIdx.x*256 + threadIdx.x;
  if (n >= NANCH) return;
  float s = scores[n];
  int B = (int)ctrl[1];
  if (bucket_of(s) >= B) {
    u32 pos = atomicAdd(&ctrl[0], 1u);
    if (pos < KCAP) {
      keybuf[pos] = ((u64)fsort(s) << 32) | (u64)(0xFFFFFFFFu - (u32)n); // ties: lower n wins
    }
  }
}

// ---------------- K6: single-block bitonic sort of 8192 u64 keys, descending ----------------
__global__ __launch_bounds__(1024) void sortk(const u64* __restrict__ keybuf, const u32* __restrict__ ctrl,
                                              u64* __restrict__ sorted) {
  __shared__ u64 s[KCAP];
  int t = threadIdx.x;
  u32 cnt = ctrl[0]; if (cnt > KCAP) cnt = KCAP;
  for (int i = t; i < KCAP; i += 1024) s[i] = (i < (int)cnt) ? keybuf[i] : 0ULL;
  __syncthreads();
  for (int size = 2; size <= KCAP; size <<= 1) {
    for (int stride = size >> 1; stride > 0; stride >>= 1) {
      for (int w = t; w < KCAP/2; w += 1024) {
        int lo = ((w & ~(stride-1)) << 1) | (w & (stride-1));
        int hi = lo + stride;
        bool desc = ((lo & size) == 0);
        u64 a = s[lo], b = s[hi];
        if ((a < b) == desc) { s[lo] = b; s[hi] = a; }
      }
      __syncthreads();
    }
  }
  for (int i = t; i < 6016; i += 1024) sorted[i] = s[i];
}

// ---------------- K6b: gather top-6000 boxes + validity bits ----------------
__global__ void gather_topk(const u64* __restrict__ sorted, const float4* __restrict__ roi,
                            float4* __restrict__ boxes, u64* __restrict__ validw) {
  int i = blockIdx.x*64 + threadIdx.x;
  bool valid = false;
  float4 b = make_float4(0.f, 0.f, 0.f, 0.f);
  if (i < PRE) {
    u64 k = sorted[i];
    if (k) {
      u32 n = 0xFFFFFFFFu - (u32)(k & 0xFFFFFFFFu);
      if (n < NANCH) { b = roi[n]; valid = (k >> 63) != 0; }
    }
  }
  boxes[i] = b;
  u64 bal = __ballot(valid);
  if (threadIdx.x == 0) validw[blockIdx.x] = bal;
}

// ---------------- K7: NMS suppression bitmask ----------------
__global__ void nms_mask(const float4* __restrict__ boxes, u64* __restrict__ mask) {
  int bi = blockIdx.y, bj = blockIdx.x;
  int t = threadIdx.x;
  int i = bi*64 + t;
  if (bj < bi) {
    if (i < PRE) mask[(size_t)i*NW + bj] = 0ULL;
    return;
  }
  __shared__ float4 cb[64];
  int j0 = bj*64;
  cb[t] = boxes[j0 + t];
  __syncthreads();
  if (i >= PRE) return;
  float4 b = boxes[i];
  float area_i = (b.z - b.x) * (b.w - b.y);
  u64 bits = 0;
  #pragma unroll 4
  for (int jj = 0; jj < 64; ++jj) {
    int j = j0 + jj;
    float4 c = cb[jj];
    float xx1 = fmaxf(b.x, c.x), yy1 = fmaxf(b.y, c.y);
    float xx2 = fminf(b.z, c.z), yy2 = fminf(b.w, c.w);
    float inter = fmaxf(xx2 - xx1, 0.f) * fmaxf(yy2 - yy1, 0.f);
    float area_j = (c.z - c.x) * (c.w - c.y);
    float iou = inter / (area_i + area_j - inter + 1e-12f);
    if (iou > 0.7f && j > i) bits |= (1ULL << jj);
  }
  mask[(size_t)i*NW + bj] = bits;
}

// ---------------- K8: sequential greedy scan + emit first 300 kept boxes ----------------
__global__ void nms_scan(const u64* __restrict__ mask, const u64* __restrict__ validw,
                         const float* __restrict__ boxes, float* __restrict__ rois) {
  int lane = threadIdx.x;
  u64 r0 = ~validw[lane];
  u64 r1 = (lane < NW-64) ? ~validw[64 + lane] : ~0ULL;
  int kept = 0;
  u64 m0 = mask[lane];
  u64 m1 = (lane < NW-64) ? mask[64 + lane] : 0ULL;
  for (int i = 0; i < PRE; ++i) {
    int wi = i >> 6;
    u64 w0 = __shfl(r0, wi & 63);
    u64 w1 = __shfl(r1, wi & 63);
    u64 wv = (wi < 64) ? w0 : w1;
    if (!((wv >> (i & 63)) & 1ULL)) {
      if (lane < 4) rois[kept*4 + lane] = boxes[(size_t)i*4 + lane];
      kept++;
      if (kept >= POST) break;
      r0 |= m0;
      if (lane < NW-64) r1 |= m1;
    }
    if (i + 1 < PRE) {
      m0 = mask[(size_t)(i+1)*NW + lane];
      m1 = (lane < NW-64) ? mask[(size_t)(i+1)*NW + 64 + lane] : 0ULL;
    }
  }
}

extern "C" void kernel_launch(void* const* d_in, const int* in_sizes, int n_in,
                              void* d_out, int out_size, void* d_ws, size_t ws_size,
                              hipStream_t stream) {
  const float* feat   = (const float*)d_in[0];
  const float* anchor = (const float*)d_in[1];
  const float* w1     = (const float*)d_in[2];
  const float* b1     = (const float*)d_in[3];
  const float* wc     = (const float*)d_in[4];
  const float* bc     = (const float*)d_in[5];
  const float* wl     = (const float*)d_in[6];
  const float* bl     = (const float*)d_in[7];
  float* out = (float*)d_out;
  char*  ws  = (char*)d_ws;
  float* wsf = (float*)d_ws;

  if (ws_size < WS_END) return;  // need ~103.5 MB

  float*    x      = wsf + X_F;
  ushort_t* p12    = (ushort_t*)(wsf + W1B_F);   // packed B planes 1+2 (f16, 9.44 MB)
  float*    wt64   = wsf + WT64_F;
  float*    b64    = wsf + B64_F;
  float*    scores = wsf + SC_F;
  float4*   roi    = (float4*)(wsf + ROI_F);
  float4*   boxes  = (float4*)(wsf + BOX_F);
  u32* hist   = (u32*)(ws + HIST_B);
  u32* ctrl   = (u32*)(ws + CTRL_B);
  u64* keybuf = (u64*)(ws + KEY_B);
  u64* sorted = (u64*)(ws + SORT_B);
  u64* validw = (u64*)(ws + VALW_B);
  u64* mask   = (u64*)(ws + MASK_B);

  hipMemsetAsync(ws + HIST_B, 0, NBINS*4 + 256, stream);
  hipMemsetAsync(out + 2160000, 0, POST*4*sizeof(float), stream);

  pack_w1b<<<9216, 256, 0, stream>>>(w1, p12);
  pack_wcl<<<129, 256, 0, stream>>>(wc, bc, wl, bl, wt64, b64);
  conv3x3_mfma<<<dim3(13, 25, 4), 512, 0, stream>>>(feat, p12, b1, x);
  conv1x1<<<313, 256, 0, stream>>>(x, wt64, b64, out);
  decode<<<1407, 256, 0, stream>>>(out, anchor, scores, roi, hist);
  scan_hist<<<1, 256, 0, stream>>>(hist, ctrl);
  compact<<<1407, 256, 0, stream>>>(scores, ctrl, keybuf);
  sortk<<<1, 1024, 0, stream>>>(keybuf, ctrl, sorted);
  gather_topk<<<NW, 64, 0, stream>>>(sorted, roi, boxes, validw);
  nms_mask<<<dim3(NW, NW), 64, 0, stream>>>(boxes, mask);
  nms_scan<<<1, 64, 0, stream>>>(mask, validw, (const float*)boxes, out + 2160000);
}

// Round 12
// 1253.288 us; speedup vs baseline: 1.9041x; 1.1194x over previous
//
#include <hip/hip_runtime.h>

typedef unsigned long long u64;
typedef unsigned int u32;
typedef unsigned short ushort_t;

#define HH 200
#define WW 200
#define HWP 40000          // 200*200 pixels
#define NANCH 360000       // HWP * 9
#define PRE 6000
#define POST 300
#define NW 94              // 64-bit mask words per NMS row (ceil(6000/64))
#define NBINS 16384
#define KCAP 8192
#define CS 40              // halo cell stride in ushorts (80B): 16B-aligned

typedef __attribute__((ext_vector_type(8))) _Float16 f16x8;
typedef __attribute__((ext_vector_type(4))) float f32x4;

// ---------------- workspace layout (unchanged footprint) ----
static constexpr size_t X_F    = 0;                          // conv1 output x[512][40000] (+64 slack)
static constexpr size_t X_CNT  = 512ULL*HWP + 64;
static constexpr size_t W1B_F  = X_F + X_CNT;                // packed B planes 1+2 (f16): 4.72M ushorts
static constexpr size_t WT64_F = W1B_F + 4608ULL*512;        // packed cls/loc weights [512][64]
static constexpr size_t B64_F  = WT64_F + 512ULL*64;         // packed bias [64]
static constexpr size_t SC_F   = B64_F + 64;                 // scores [360000]
static constexpr size_t ROI_F  = SC_F + NANCH;               // decoded boxes [360000][4]
static constexpr size_t BOX_F  = ROI_F + 4ULL*NANCH;         // top-6000 boxes (pad 6016) [4]
static constexpr size_t FEND_F = BOX_F + 6016ULL*4;
static constexpr size_t HIST_B = ((FEND_F*4 + 255)/256)*256; // u32[16384]
static constexpr size_t CTRL_B = HIST_B + NBINS*4;           // u32[64]: [0]=cnt, [1]=cutoff bucket
static constexpr size_t KEY_B  = CTRL_B + 256;               // u64[8192] candidate keys
static constexpr size_t SORT_B = KEY_B + (size_t)KCAP*8;     // u64[6016] sorted keys
static constexpr size_t VALW_B = SORT_B + 6016ULL*8;         // u64[94] validity bits
static constexpr size_t MASK_B = ((VALW_B + NW*8 + 255)/256)*256; // u64[6000][94] NMS mask
static constexpr size_t WS_END = MASK_B + (size_t)PRE*NW*8;  // ~103.5 MB total

// ---------------- helpers ----------------
__device__ __forceinline__ u32 fsort(float f) {
  u32 u = __float_as_uint(f);
  return (u & 0x80000000u) ? ~u : (u | 0x80000000u);
}
__device__ __forceinline__ int bucket_of(float s) {
  int b = (int)((s + 1.0f) * 8191.0f);
  return b < 0 ? 0 : (b > 16383 ? 16383 : b);
}
__device__ __forceinline__ ushort_t h_bits(_Float16 h) {
  union { _Float16 h; ushort_t u; } c; c.h = h; return c.u;
}
// f16x2 split of a float pair -> two packed u32 (plane1: h1, plane2: h2*2048)
__device__ __forceinline__ void split_pack(float fA, float fB, u32& w1, u32& w2) {
  _Float16 hA = (_Float16)fA, hB = (_Float16)fB;
  float rA = fA - (float)hA, rB = fB - (float)hB;
  _Float16 cA = (_Float16)(rA * 2048.0f), cB = (_Float16)(rB * 2048.0f);
  w1 = (u32)h_bits(hA) | ((u32)h_bits(hB) << 16);
  w2 = (u32)h_bits(cA) | ((u32)h_bits(cB) << 16);
}

// single-x halo load (one ci-pair): raw floats, no split
__device__ __forceinline__ void halo_load1(const float* __restrict__ fbn, int y, int y0, int x0,
                                           int x, float& a0, float& b0) {
  int gy = y0 + y - 1, gx = x0 + x - 1;
  bool ok = ((unsigned)gy < 200u) && ((unsigned)gx < 200u);
  int off = ok ? (gy*200 + gx) : 0;
  float fA = fbn[off], fB = fbn[off + HWP];
  a0 = ok ? fA : 0.f;  b0 = ok ? fB : 0.f;
}
// linear write (NO swizzle -- R8 measured: XOR swizzle RAISED conflicts 1.8x)
__device__ __forceinline__ void halo_write1(u32* __restrict__ H1u, u32* __restrict__ H2u,
                                            int y, int x, int cih, float a0, float b0) {
  u32 w1v, w2v;
  split_pack(a0, b0, w1v, w2v);
  int idx = (y*18 + x)*(CS/2) + cih;
  H1u[idx] = w1v;
  H2u[idx] = w2v;
}
// 2-row batches: only 4 floats live per batch per thread
template<int Y0>
__device__ __forceinline__ void halo_load2(const float* __restrict__ fbn, int y0, int x0,
                                           int x, float* sA, float* sB) {
  #pragma unroll
  for (int yy = 0; yy < 2; ++yy)
    halo_load1(fbn, Y0 + yy, y0, x0, x, sA[yy], sB[yy]);
}
template<int Y0>
__device__ __forceinline__ void halo_write2(u32* __restrict__ H1u, u32* __restrict__ H2u,
                                            int x, int cih, float* sA, float* sB) {
  #pragma unroll
  for (int yy = 0; yy < 2; ++yy)
    halo_write1(H1u, H2u, Y0 + yy, x, cih, sA[yy], sB[yy]);
}

// ---------------- K0a: prepack w1 -> 2 f16 planes (h1, h2*2048), TAP-MAJOR k-order ----
// step s = chunk*9 + tap (chunk = ci>>5), within-step k-index = ci&31.
// R6 grouping (harness-verified at 753us): wnb = oz>>5 (4 groups of 32 och),
// j = (oz>>4)&1. fragment: p12[(((z*144+s)*4+wnb)*2+j)*1024 + p*512 + lane*8 + e]
__global__ void pack_w1b(const float* __restrict__ w1, ushort_t* __restrict__ p12) {
  int idx = blockIdx.x*256 + threadIdx.x;
  if (idx >= 512*4608) return;
  int och = idx / 4608, k = idx - (idx/4608)*4608;   // k = ci*9 + tap (reference order)
  float f = w1[idx];
  _Float16 h1 = (_Float16)f;
  float r = f - (float)h1;
  _Float16 h2 = (_Float16)(r * 2048.0f);
  int ci = k / 9, tap = k - ci*9;
  int chunk = ci >> 5, cil = ci & 31;
  int s = chunk*9 + tap;
  int z = och >> 7, oz = och & 127;
  int wnb = oz >> 5, j = (oz >> 4) & 1, lmm = oz & 15;
  int lg = cil >> 3, e = cil & 7;
  int lane = lg*16 + lmm;
  size_t base = (((size_t)z*144 + s)*4 + wnb)*2 + j;
  p12[base*1024 +       lane*8 + e] = h_bits(h1);
  p12[base*1024 + 512 + lane*8 + e] = h_bits(h2);
}

// ---------------- K0b: pack wc(18)/wl(36) -> wt[ci][64] (zero-padded), bias[64] ----------------
__global__ void pack_wcl(const float* __restrict__ wc, const float* __restrict__ bc,
                         const float* __restrict__ wl, const float* __restrict__ bl,
                         float* __restrict__ wt, float* __restrict__ b64) {
  int idx = blockIdx.x*256 + threadIdx.x;
  if (idx < 512*64) {
    int ci = idx >> 6, o = idx & 63;
    float v = 0.f;
    if (o < 18) v = wc[o*512 + ci];
    else if (o < 54) v = wl[(o-18)*512 + ci];
    wt[idx] = v;
  } else if (idx < 512*64 + 64) {
    int o = idx - 512*64;
    float v = 0.f;
    if (o < 18) v = bc[o]; else if (o < 54) v = bl[o-18];
    b64[o] = v;
  }
}

// ---------------- K1: 3x3 conv 512->512 + ReLU, f16x2 split, halo-LDS tap-major ----------
// R12 = R6 VERBATIM (best verified: conv 753us, total 1252us). R7-R11 post-mortems:
// every schedule/decomposition/swizzle/occupancy/phase variant regressed. 2M x 4N,
// 8 waves, acc 64 VGPR + ~124 arch at (512,2); halo double-buffer (1 barrier/chunk);
// T14 2-row staging batches at taps 0-5; fb 1-ahead prefetch.
__global__ __launch_bounds__(512, 2) void conv3x3_mfma(const float* __restrict__ feat,
    const ushort_t* __restrict__ p12,
    const float* __restrict__ b1, float* __restrict__ xout) {
  __shared__ ushort_t H1[2][10*18*CS], H2[2][10*18*CS];   // double-buffered halo, 57.6KB
  const int t = threadIdx.x;
  const int x0 = blockIdx.x*16, y0 = blockIdx.y*8;
  const int zi = blockIdx.z;
  const int ob = zi*128;

  const int wave = t >> 6, lane = t & 63;
  const int wm = (wave & 1)*64;            // M half (64 pixels)
  const int wnb = wave >> 1;               // N quarter (32 och)
  const int lm = lane & 15, lg = lane >> 4;
  const int lyb = (wave & 1)*4;            // tile-row base of this wave's M
  const int fragoff = lm*CS + lg*8;        // per-lane ushort offset into a halo row

  // staging map: cih = t>>5 (ci pair 0..15), x-slot = t&31 (active if <18)
  const int cih = t >> 5;
  const int sxo = t & 31;
  const bool act = sxo < 18;

  f32x4 accM[4][2], accC[4][2];
  #pragma unroll
  for (int i = 0; i < 4; ++i)
    #pragma unroll
    for (int j = 0; j < 2; ++j) {
      accM[i][j] = (f32x4){0.f, 0.f, 0.f, 0.f};
      accC[i][j] = (f32x4){0.f, 0.f, 0.f, 0.f};
    }

  float sA[2], sB[2];                      // one 2-row staging batch (4 floats)

  // ---- prologue: stage chunk 0 into buffer 0 (5 sequential 2-row batches) ----
  {
    const float* fbn = feat + (size_t)(2*cih)*HWP;
    u32* h1n = (u32*)H1[0];  u32* h2n = (u32*)H2[0];
    if (act) {
      halo_load2<0>(fbn, y0, x0, sxo, sA, sB);
      halo_write2<0>(h1n, h2n, sxo, cih, sA, sB);
      halo_load2<2>(fbn, y0, x0, sxo, sA, sB);
      halo_write2<2>(h1n, h2n, sxo, cih, sA, sB);
      halo_load2<4>(fbn, y0, x0, sxo, sA, sB);
      halo_write2<4>(h1n, h2n, sxo, cih, sA, sB);
      halo_load2<6>(fbn, y0, x0, sxo, sA, sB);
      halo_write2<6>(h1n, h2n, sxo, cih, sA, sB);
      halo_load2<8>(fbn, y0, x0, sxo, sA, sB);
      halo_write2<8>(h1n, h2n, sxo, cih, sA, sB);
    }
  }

  // ---- preload fb pair for (s=0, j=0) ----
  const ushort_t* pb = p12 + (size_t)zi*1179648 + (size_t)wnb*2048 + lane*8;
  f16x8 nb1 = *(const f16x8*)pb;
  f16x8 nb2 = *(const f16x8*)(pb + 512);

  for (int c = 0; c < 16; ++c) {
    __syncthreads();   // buf[c&1] ready; all reads of buf[(c+1)&1] (iter c-1) done
    const ushort_t* h1c = H1[c & 1];
    const ushort_t* h2c = H2[c & 1];
    u32* h1n = (u32*)H1[(c + 1) & 1];
    u32* h2n = (u32*)H2[(c + 1) & 1];
    const float* fbn = feat + (size_t)(2*cih)*HWP + (size_t)(c + 1)*32*HWP;
    const bool stg = act && (c < 15);

    #pragma unroll 1
    for (int tap = 0; tap < 9; ++tap) {
      const int dy = tap/3, dx = tap - (tap/3)*3;
      // ---- A fragments: 8 ds_read_b128 (linear layout), issued first ----
      f16x8 fa1[4], fa2[4];
      #pragma unroll
      for (int i = 0; i < 4; ++i) {
        int addr = (lyb + i + dy)*(18*CS) + dx*CS + fragoff;
        fa1[i] = *(const f16x8*)&h1c[addr];
        fa2[i] = *(const f16x8*)&h2c[addr];
      }
      // ---- T14 staging: load batch @ tap k, write @ tap k+1 (1 batch live) ----
      if (stg) {
        if (tap == 0) {
          halo_load2<0>(fbn, y0, x0, sxo, sA, sB);
        } else if (tap == 1) {
          halo_write2<0>(h1n, h2n, sxo, cih, sA, sB);
          halo_load2<2>(fbn, y0, x0, sxo, sA, sB);
        } else if (tap == 2) {
          halo_write2<2>(h1n, h2n, sxo, cih, sA, sB);
          halo_load2<4>(fbn, y0, x0, sxo, sA, sB);
        } else if (tap == 3) {
          halo_write2<4>(h1n, h2n, sxo, cih, sA, sB);
          halo_load2<6>(fbn, y0, x0, sxo, sA, sB);
        } else if (tap == 4) {
          halo_write2<6>(h1n, h2n, sxo, cih, sA, sB);
          halo_load2<8>(fbn, y0, x0, sxo, sA, sB);
        } else if (tap == 5) {
          halo_write2<8>(h1n, h2n, sxo, cih, sA, sB);
        }
      }
      // ---- 2 j-stages: {consume prefetched pair; prefetch next; 12 MFMA} ----
      const bool lastS = (c == 15) && (tap == 8);
      const ushort_t* pbn = lastS ? pb : (pb + 8192);
      #pragma unroll
      for (int j = 0; j < 2; ++j) {
        f16x8 cb1 = nb1, cb2 = nb2;
        const ushort_t* nx = (j < 1) ? (pb + 1024) : pbn;
        nb1 = *(const f16x8*)nx;
        nb2 = *(const f16x8*)(nx + 512);
        #pragma unroll
        for (int i = 0; i < 4; ++i) {
          accM[i][j] = __builtin_amdgcn_mfma_f32_16x16x32_f16(fa1[i], cb1, accM[i][j], 0, 0, 0);
          accC[i][j] = __builtin_amdgcn_mfma_f32_16x16x32_f16(fa1[i], cb2, accC[i][j], 0, 0, 0);
          accC[i][j] = __builtin_amdgcn_mfma_f32_16x16x32_f16(fa2[i], cb1, accC[i][j], 0, 0, 0);
        }
      }
      pb = pbn;
    }
  }

  // epilogue: combine main + scaled cross, bias + relu, store x[och][pixel]
  #pragma unroll
  for (int i = 0; i < 4; ++i) {
    int prow = wm + i*16 + lg*4;
    #pragma unroll
    for (int j = 0; j < 2; ++j) {
      int o = ob + wnb*32 + j*16 + lm;
      float bias = b1[o];
      #pragma unroll
      for (int r = 0; r < 4; ++r) {
        int p  = prow + r;
        int yy = y0 + (p >> 4), xx = x0 + (p & 15);
        if (xx < WW) {
          float v = accM[i][j][r] + accC[i][j][r] * 4.8828125e-4f + bias; // 2^-11
          xout[(size_t)o*HWP + yy*200 + xx] = fmaxf(v, 0.f);
        }
      }
    }
  }
}

// ---------------- K2: 1x1 convs (cls+loc) as GEMM [40000 x 64] = x^T[40000x512] * wt[512x64] ----
__global__ __launch_bounds__(256, 4) void conv1x1(const float* __restrict__ x,
                                                  const float* __restrict__ wt,
                                                  const float* __restrict__ bias,
                                                  float* __restrict__ out) {
  __shared__ float Xs[16*128];
  __shared__ float Ws[16*64];
  const int t = threadIdx.x;
  const int m0 = blockIdx.x*128;
  float acc[32];
  #pragma unroll
  for (int i = 0; i < 32; ++i) acc[i] = 0.f;
  const int mb = t & 15, nb = t >> 4;
  const int mm = t & 127, hh = t >> 7;
  const int nn = t & 63,  h2 = t >> 6;

  for (int kb = 0; kb < 512; kb += 16) {
    #pragma unroll
    for (int j = 0; j < 8; ++j) {
      int kk = hh + 2*j;
      Xs[kk*128 + mm] = x[(size_t)(kb+kk)*HWP + m0 + mm];
    }
    #pragma unroll
    for (int j = 0; j < 4; ++j) {
      int kk = h2 + 4*j;
      Ws[kk*64 + nn] = wt[(size_t)(kb+kk)*64 + nn];
    }
    __syncthreads();
    #pragma unroll
    for (int kk = 0; kk < 16; ++kk) {
      float av[8], bv[4];
      *(float4*)&av[0] = *(const float4*)&Xs[kk*128 + mb*8];
      *(float4*)&av[4] = *(const float4*)&Xs[kk*128 + mb*8 + 4];
      *(float4*)&bv[0] = *(const float4*)&Ws[kk*64 + nb*4];
      #pragma unroll
      for (int i = 0; i < 8; ++i)
        #pragma unroll
        for (int jj = 0; jj < 4; ++jj)
          acc[i*4+jj] = fmaf(av[i], bv[jj], acc[i*4+jj]);
    }
    __syncthreads();
  }

  #pragma unroll
  for (int jj = 0; jj < 4; ++jj) {
    int o = nb*4 + jj;
    float bv = bias[o];
    #pragma unroll
    for (int i = 0; i < 8; ++i) {
      int mm2 = m0 + mb*8 + i;
      if (mm2 < HWP) {
        float v = acc[i*4+jj] + bv;
        if (o < 18)       out[(size_t)mm2*18 + o] = v;               // pred_cls: [m][2a+c]
        else if (o < 54)  out[720000 + (size_t)mm2*36 + (o-18)] = v; // pred_loc: [m][4a+j]
      }
    }
  }
}

// ---------------- K3: decode boxes + score + histogram ----------------
__global__ void decode(const float* __restrict__ dout, const float* __restrict__ anchor,
                       float* __restrict__ scores, float4* __restrict__ roi, u32* __restrict__ hist) {
  int n = blockIdx.x*256 + threadIdx.x;
  if (n >= NANCH) return;
  int mq = n / 9;
  int a  = n - mq*9;
  float c0 = dout[(size_t)mq*18 + 2*a];
  float c1 = dout[(size_t)mq*18 + 2*a + 1];
  float score = 1.0f / (1.0f + expf(c0 - c1));  // == softmax[:,1]; monotone in (c1-c0)
  const float* lp = dout + 720000 + (size_t)mq*36 + 4*a;
  float l0 = lp[0], l1 = lp[1], l2 = lp[2], l3 = lp[3];
  float4 an = ((const float4*)anchor)[n];
  float aw = an.z - an.x, ah = an.w - an.y;
  float acx = (an.x + an.z)*0.5f, acy = (an.y + an.w)*0.5f;
  float cx = l0*aw + acx, cy = l1*ah + acy;
  float bw = expf(l2)*aw, bh = expf(l3)*ah;
  float x1 = fminf(fmaxf(cx - bw*0.5f, 0.f), 1.f);
  float y1 = fminf(fmaxf(cy - bh*0.5f, 0.f), 1.f);
  float x2 = fminf(fmaxf(cx + bw*0.5f, 0.f), 1.f);
  float y2 = fminf(fmaxf(cy + bh*0.5f, 0.f), 1.f);
  bool valid = ((y2 - y1) >= 0.016f) && ((x2 - x1) >= 0.016f);
  float sc = valid ? score : -1.0f;
  scores[n] = sc;
  roi[n] = make_float4(x1, y1, x2, y2);
  atomicAdd(&hist[bucket_of(sc)], 1u);
}

// ---------------- K4: find cutoff bucket B ----------------
__global__ void scan_hist(const u32* __restrict__ hist, u32* __restrict__ ctrl) {
  __shared__ u32 seg[256];
  int t = threadIdx.x;
  u32 s = 0;
  for (int b = 0; b < 64; ++b) s += hist[t*64 + b];
  seg[t] = s;
  __syncthreads();
  if (t == 0) {
    u32 cum = 0; int B = 0;
    for (int sg = 255; sg >= 0; --sg) {
      if (cum + seg[sg] >= PRE) {
        for (int b = sg*64 + 63; b >= sg*64; --b) {
          cum += hist[b];
          if (cum >= PRE) { B = b; break; }
        }
        break;
      }
      cum += seg[sg];
    }
    ctrl[1] = (u32)B;
  }
}

// ---------------- K5: compact candidates (bucket >= B) into keybuf ----------------
__global__ void compact(const float* __restrict__ scores, u32* __restrict__ ctrl, u64* __restrict__ keybuf) {
  int n = blockIdx.x*256 + threadIdx.x;
  if (n >= NANCH) return;
  float s = scores[n];
  int B = (int)ctrl[1];
  if (bucket_of(s) >= B) {
    u32 pos = atomicAdd(&ctrl[0], 1u);
    if (pos < KCAP) {
      keybuf[pos] = ((u64)fsort(s) << 32) | (u64)(0xFFFFFFFFu - (u32)n); // ties: lower n wins
    }
  }
}

// ---------------- K6: single-block bitonic sort of 8192 u64 keys, descending ----------------
__global__ __launch_bounds__(1024) void sortk(const u64* __restrict__ keybuf, const u32* __restrict__ ctrl,
                                              u64* __restrict__ sorted) {
  __shared__ u64 s[KCAP];
  int t = threadIdx.x;
  u32 cnt = ctrl[0]; if (cnt > KCAP) cnt = KCAP;
  for (int i = t; i < KCAP; i += 1024) s[i] = (i < (int)cnt) ? keybuf[i] : 0ULL;
  __syncthreads();
  for (int size = 2; size <= KCAP; size <<= 1) {
    for (int stride = size >> 1; stride > 0; stride >>= 1) {
      for (int w = t; w < KCAP/2; w += 1024) {
        int lo = ((w & ~(stride-1)) << 1) | (w & (stride-1));
        int hi = lo + stride;
        bool desc = ((lo & size) == 0);
        u64 a = s[lo], b = s[hi];
        if ((a < b) == desc) { s[lo] = b; s[hi] = a; }
      }
      __syncthreads();
    }
  }
  for (int i = t; i < 6016; i += 1024) sorted[i] = s[i];
}

// ---------------- K6b: gather top-6000 boxes + validity bits ----------------
__global__ void gather_topk(const u64* __restrict__ sorted, const float4* __restrict__ roi,
                            float4* __restrict__ boxes, u64* __restrict__ validw) {
  int i = blockIdx.x*64 + threadIdx.x;
  bool valid = false;
  float4 b = make_float4(0.f, 0.f, 0.f, 0.f);
  if (i < PRE) {
    u64 k = sorted[i];
    if (k) {
      u32 n = 0xFFFFFFFFu - (u32)(k & 0xFFFFFFFFu);
      if (n < NANCH) { b = roi[n]; valid = (k >> 63) != 0; }
    }
  }
  boxes[i] = b;
  u64 bal = __ballot(valid);
  if (threadIdx.x == 0) validw[blockIdx.x] = bal;
}

// ---------------- K7: NMS suppression bitmask ----------------
__global__ void nms_mask(const float4* __restrict__ boxes, u64* __restrict__ mask) {
  int bi = blockIdx.y, bj = blockIdx.x;
  int t = threadIdx.x;
  int i = bi*64 + t;
  if (bj < bi) {
    if (i < PRE) mask[(size_t)i*NW + bj] = 0ULL;
    return;
  }
  __shared__ float4 cb[64];
  int j0 = bj*64;
  cb[t] = boxes[j0 + t];
  __syncthreads();
  if (i >= PRE) return;
  float4 b = boxes[i];
  float area_i = (b.z - b.x) * (b.w - b.y);
  u64 bits = 0;
  #pragma unroll 4
  for (int jj = 0; jj < 64; ++jj) {
    int j = j0 + jj;
    float4 c = cb[jj];
    float xx1 = fmaxf(b.x, c.x), yy1 = fmaxf(b.y, c.y);
    float xx2 = fminf(b.z, c.z), yy2 = fminf(b.w, c.w);
    float inter = fmaxf(xx2 - xx1, 0.f) * fmaxf(yy2 - yy1, 0.f);
    float area_j = (c.z - c.x) * (c.w - c.y);
    float iou = inter / (area_i + area_j - inter + 1e-12f);
    if (iou > 0.7f && j > i) bits |= (1ULL << jj);
  }
  mask[(size_t)i*NW + bj] = bits;
}

// ---------------- K8: sequential greedy scan, 8-deep mask-row prefetch ring ----------------
// R12: the old loop held ONE row in flight (WAW on m0/m1 forces a vmcnt wait each of
// 6000 iterations -> per-step ~L2/L3 latency, est. 150-400us). Rows advance
// unconditionally, so an 8-deep named-slot ring (rule #20: static indices only,
// 16 u64 = 32 VGPRs, single-wave kernel) gives each load ~8 steps of slack:
// per-step cost -> max(ALU ~50cy, latency/8). Greedy r-chain semantics unchanged.
__global__ void nms_scan(const u64* __restrict__ mask, const u64* __restrict__ validw,
                         const float* __restrict__ boxes, float* __restrict__ rois) {
  int lane = threadIdx.x;
  const bool hi = lane < NW-64;
  u64 r0 = ~validw[lane];
  u64 r1 = hi ? ~validw[64 + lane] : ~0ULL;
  int kept = 0;
  u64 a0,a1,b0,b1,c0,c1,d0,d1,e0,e1,f0,f1,g0,g1,h0,h1;
#define LOADR(S0,S1,ROW) { S0 = mask[(size_t)(ROW)*NW + lane]; S1 = hi ? mask[(size_t)(ROW)*NW + 64 + lane] : 0ULL; }
  LOADR(a0,a1,0) LOADR(b0,b1,1) LOADR(c0,c1,2) LOADR(d0,d1,3)
  LOADR(e0,e1,4) LOADR(f0,f1,5) LOADR(g0,g1,6) LOADR(h0,h1,7)
#define STEP(S0,S1,II) { \
    int wi = (II) >> 6; \
    u64 w0 = __shfl(r0, wi & 63); \
    u64 w1 = __shfl(r1, wi & 63); \
    u64 wv = (wi < 64) ? w0 : w1; \
    if (!((wv >> ((II) & 63)) & 1ULL)) { \
      if (lane < 4) rois[kept*4 + lane] = boxes[(size_t)(II)*4 + lane]; \
      kept++; \
      if (kept >= POST) goto done; \
      r0 |= S0; \
      if (hi) r1 |= S1; \
    } \
    if ((II) + 8 < PRE) LOADR(S0, S1, (II)+8) }
  for (int i = 0; i < PRE; i += 8) {
    STEP(a0,a1,i)   STEP(b0,b1,i+1) STEP(c0,c1,i+2) STEP(d0,d1,i+3)
    STEP(e0,e1,i+4) STEP(f0,f1,i+5) STEP(g0,g1,i+6) STEP(h0,h1,i+7)
  }
done: ;
#undef STEP
#undef LOADR
}

extern "C" void kernel_launch(void* const* d_in, const int* in_sizes, int n_in,
                              void* d_out, int out_size, void* d_ws, size_t ws_size,
                              hipStream_t stream) {
  const float* feat   = (const float*)d_in[0];
  const float* anchor = (const float*)d_in[1];
  const float* w1     = (const float*)d_in[2];
  const float* b1     = (const float*)d_in[3];
  const float* wc     = (const float*)d_in[4];
  const float* bc     = (const float*)d_in[5];
  const float* wl     = (const float*)d_in[6];
  const float* bl     = (const float*)d_in[7];
  float* out = (float*)d_out;
  char*  ws  = (char*)d_ws;
  float* wsf = (float*)d_ws;

  if (ws_size < WS_END) return;  // need ~103.5 MB

  float*    x      = wsf + X_F;
  ushort_t* p12    = (ushort_t*)(wsf + W1B_F);   // packed B planes 1+2 (f16, 9.44 MB)
  float*    wt64   = wsf + WT64_F;
  float*    b64    = wsf + B64_F;
  float*    scores = wsf + SC_F;
  float4*   roi    = (float4*)(wsf + ROI_F);
  float4*   boxes  = (float4*)(wsf + BOX_F);
  u32* hist   = (u32*)(ws + HIST_B);
  u32* ctrl   = (u32*)(ws + CTRL_B);
  u64* keybuf = (u64*)(ws + KEY_B);
  u64* sorted = (u64*)(ws + SORT_B);
  u64* validw = (u64*)(ws + VALW_B);
  u64* mask   = (u64*)(ws + MASK_B);

  hipMemsetAsync(ws + HIST_B, 0, NBINS*4 + 256, stream);
  hipMemsetAsync(out + 2160000, 0, POST*4*sizeof(float), stream);

  pack_w1b<<<9216, 256, 0, stream>>>(w1, p12);
  pack_wcl<<<129, 256, 0, stream>>>(wc, bc, wl, bl, wt64, b64);
  conv3x3_mfma<<<dim3(13, 25, 4), 512, 0, stream>>>(feat, p12, b1, x);
  conv1x1<<<313, 256, 0, stream>>>(x, wt64, b64, out);
  decode<<<1407, 256, 0, stream>>>(out, anchor, scores, roi, hist);
  scan_hist<<<1, 256, 0, stream>>>(hist, ctrl);
  compact<<<1407, 256, 0, stream>>>(scores, ctrl, keybuf);
  sortk<<<1, 1024, 0, stream>>>(keybuf, ctrl, sorted);
  gather_topk<<<NW, 64, 0, stream>>>(sorted, roi, boxes, validw);
  nms_mask<<<dim3(NW, NW), 64, 0, stream>>>(boxes, mask);
  nms_scan<<<1, 64, 0, stream>>>(mask, validw, (const float*)boxes, out + 2160000);
}

// Round 13
// 1238.762 us; speedup vs baseline: 1.9264x; 1.0117x over previous
//
#include <hip/hip_runtime.h>

typedef unsigned long long u64;
typedef unsigned int u32;
typedef unsigned short ushort_t;

#define HH 200
#define WW 200
#define HWP 40000          // 200*200 pixels
#define NANCH 360000       // HWP * 9
#define PRE 6000
#define POST 300
#define NW 94              // 64-bit mask words per NMS row (ceil(6000/64))
#define NBINS 16384
#define KCAP 8192
#define CS 40              // halo cell stride in ushorts (80B): 16B-aligned

typedef __attribute__((ext_vector_type(8))) _Float16 f16x8;
typedef __attribute__((ext_vector_type(4))) float f32x4;

// ---------------- workspace layout (unchanged footprint) ----
static constexpr size_t X_F    = 0;                          // conv1 output x[512][40000] (+64 slack)
static constexpr size_t X_CNT  = 512ULL*HWP + 64;
static constexpr size_t W1B_F  = X_F + X_CNT;                // packed B planes 1+2 (f16): 4.72M ushorts
static constexpr size_t WT64_F = W1B_F + 4608ULL*512;        // packed cls/loc weights [512][64]
static constexpr size_t B64_F  = WT64_F + 512ULL*64;         // packed bias [64]
static constexpr size_t SC_F   = B64_F + 64;                 // scores [360000]
static constexpr size_t ROI_F  = SC_F + NANCH;               // decoded boxes [360000][4]
static constexpr size_t BOX_F  = ROI_F + 4ULL*NANCH;         // top-6000 boxes (pad 6016) [4]
static constexpr size_t FEND_F = BOX_F + 6016ULL*4;
static constexpr size_t HIST_B = ((FEND_F*4 + 255)/256)*256; // u32[16384]
static constexpr size_t CTRL_B = HIST_B + NBINS*4;           // u32[64]: [0]=cnt, [1]=cutoff bucket
static constexpr size_t KEY_B  = CTRL_B + 256;               // u64[8192] candidate keys
static constexpr size_t SORT_B = KEY_B + (size_t)KCAP*8;     // u64[6016] sorted keys
static constexpr size_t VALW_B = SORT_B + 6016ULL*8;         // u64[94] validity bits
static constexpr size_t MASK_B = ((VALW_B + NW*8 + 255)/256)*256; // u64[6000][94] NMS mask
static constexpr size_t WS_END = MASK_B + (size_t)PRE*NW*8;  // ~103.5 MB total

// ---------------- helpers ----------------
__device__ __forceinline__ u32 fsort(float f) {
  u32 u = __float_as_uint(f);
  return (u & 0x80000000u) ? ~u : (u | 0x80000000u);
}
__device__ __forceinline__ int bucket_of(float s) {
  int b = (int)((s + 1.0f) * 8191.0f);
  return b < 0 ? 0 : (b > 16383 ? 16383 : b);
}
__device__ __forceinline__ ushort_t h_bits(_Float16 h) {
  union { _Float16 h; ushort_t u; } c; c.h = h; return c.u;
}
// f16x2 split of a float pair -> two packed u32 (plane1: h1, plane2: h2*2048)
__device__ __forceinline__ void split_pack(float fA, float fB, u32& w1, u32& w2) {
  _Float16 hA = (_Float16)fA, hB = (_Float16)fB;
  float rA = fA - (float)hA, rB = fB - (float)hB;
  _Float16 cA = (_Float16)(rA * 2048.0f), cB = (_Float16)(rB * 2048.0f);
  w1 = (u32)h_bits(hA) | ((u32)h_bits(hB) << 16);
  w2 = (u32)h_bits(cA) | ((u32)h_bits(cB) << 16);
}

// single-x halo load (one ci-pair): raw floats, no split
__device__ __forceinline__ void halo_load1(const float* __restrict__ fbn, int y, int y0, int x0,
                                           int x, float& a0, float& b0) {
  int gy = y0 + y - 1, gx = x0 + x - 1;
  bool ok = ((unsigned)gy < 200u) && ((unsigned)gx < 200u);
  int off = ok ? (gy*200 + gx) : 0;
  float fA = fbn[off], fB = fbn[off + HWP];
  a0 = ok ? fA : 0.f;  b0 = ok ? fB : 0.f;
}
// linear write (NO swizzle -- R8 measured: XOR swizzle RAISED conflicts 1.8x)
__device__ __forceinline__ void halo_write1(u32* __restrict__ H1u, u32* __restrict__ H2u,
                                            int y, int x, int cih, float a0, float b0) {
  u32 w1v, w2v;
  split_pack(a0, b0, w1v, w2v);
  int idx = (y*18 + x)*(CS/2) + cih;
  H1u[idx] = w1v;
  H2u[idx] = w2v;
}
// 2-row batches: only 4 floats live per batch per thread
template<int Y0>
__device__ __forceinline__ void halo_load2(const float* __restrict__ fbn, int y0, int x0,
                                           int x, float* sA, float* sB) {
  #pragma unroll
  for (int yy = 0; yy < 2; ++yy)
    halo_load1(fbn, Y0 + yy, y0, x0, x, sA[yy], sB[yy]);
}
template<int Y0>
__device__ __forceinline__ void halo_write2(u32* __restrict__ H1u, u32* __restrict__ H2u,
                                            int x, int cih, float* sA, float* sB) {
  #pragma unroll
  for (int yy = 0; yy < 2; ++yy)
    halo_write1(H1u, H2u, Y0 + yy, x, cih, sA[yy], sB[yy]);
}

// ---------------- K0a: prepack w1 -> 2 f16 planes (h1, h2*2048), TAP-MAJOR k-order ----
// step s = chunk*9 + tap (chunk = ci>>5), within-step k-index = ci&31.
// R6 grouping (harness-verified at 753us): wnb = oz>>5 (4 groups of 32 och),
// j = (oz>>4)&1. fragment: p12[(((z*144+s)*4+wnb)*2+j)*1024 + p*512 + lane*8 + e]
__global__ void pack_w1b(const float* __restrict__ w1, ushort_t* __restrict__ p12) {
  int idx = blockIdx.x*256 + threadIdx.x;
  if (idx >= 512*4608) return;
  int och = idx / 4608, k = idx - (idx/4608)*4608;   // k = ci*9 + tap (reference order)
  float f = w1[idx];
  _Float16 h1 = (_Float16)f;
  float r = f - (float)h1;
  _Float16 h2 = (_Float16)(r * 2048.0f);
  int ci = k / 9, tap = k - ci*9;
  int chunk = ci >> 5, cil = ci & 31;
  int s = chunk*9 + tap;
  int z = och >> 7, oz = och & 127;
  int wnb = oz >> 5, j = (oz >> 4) & 1, lmm = oz & 15;
  int lg = cil >> 3, e = cil & 7;
  int lane = lg*16 + lmm;
  size_t base = (((size_t)z*144 + s)*4 + wnb)*2 + j;
  p12[base*1024 +       lane*8 + e] = h_bits(h1);
  p12[base*1024 + 512 + lane*8 + e] = h_bits(h2);
}

// ---------------- K0b: pack wc(18)/wl(36) -> wt[ci][64] (zero-padded), bias[64] ----------------
__global__ void pack_wcl(const float* __restrict__ wc, const float* __restrict__ bc,
                         const float* __restrict__ wl, const float* __restrict__ bl,
                         float* __restrict__ wt, float* __restrict__ b64) {
  int idx = blockIdx.x*256 + threadIdx.x;
  if (idx < 512*64) {
    int ci = idx >> 6, o = idx & 63;
    float v = 0.f;
    if (o < 18) v = wc[o*512 + ci];
    else if (o < 54) v = wl[(o-18)*512 + ci];
    wt[idx] = v;
  } else if (idx < 512*64 + 64) {
    int o = idx - 512*64;
    float v = 0.f;
    if (o < 18) v = bc[o]; else if (o < 54) v = bl[o-18];
    b64[o] = v;
  }
}

// ---------------- K1: 3x3 conv 512->512 + ReLU, f16x2 split, halo-LDS tap-major ----------
// R13 = R6 VERBATIM (best verified: conv 748-753us; R7-R11 all regressed; frozen).
__global__ __launch_bounds__(512, 2) void conv3x3_mfma(const float* __restrict__ feat,
    const ushort_t* __restrict__ p12,
    const float* __restrict__ b1, float* __restrict__ xout) {
  __shared__ ushort_t H1[2][10*18*CS], H2[2][10*18*CS];   // double-buffered halo, 57.6KB
  const int t = threadIdx.x;
  const int x0 = blockIdx.x*16, y0 = blockIdx.y*8;
  const int zi = blockIdx.z;
  const int ob = zi*128;

  const int wave = t >> 6, lane = t & 63;
  const int wm = (wave & 1)*64;            // M half (64 pixels)
  const int wnb = wave >> 1;               // N quarter (32 och)
  const int lm = lane & 15, lg = lane >> 4;
  const int lyb = (wave & 1)*4;            // tile-row base of this wave's M
  const int fragoff = lm*CS + lg*8;        // per-lane ushort offset into a halo row

  // staging map: cih = t>>5 (ci pair 0..15), x-slot = t&31 (active if <18)
  const int cih = t >> 5;
  const int sxo = t & 31;
  const bool act = sxo < 18;

  f32x4 accM[4][2], accC[4][2];
  #pragma unroll
  for (int i = 0; i < 4; ++i)
    #pragma unroll
    for (int j = 0; j < 2; ++j) {
      accM[i][j] = (f32x4){0.f, 0.f, 0.f, 0.f};
      accC[i][j] = (f32x4){0.f, 0.f, 0.f, 0.f};
    }

  float sA[2], sB[2];                      // one 2-row staging batch (4 floats)

  // ---- prologue: stage chunk 0 into buffer 0 (5 sequential 2-row batches) ----
  {
    const float* fbn = feat + (size_t)(2*cih)*HWP;
    u32* h1n = (u32*)H1[0];  u32* h2n = (u32*)H2[0];
    if (act) {
      halo_load2<0>(fbn, y0, x0, sxo, sA, sB);
      halo_write2<0>(h1n, h2n, sxo, cih, sA, sB);
      halo_load2<2>(fbn, y0, x0, sxo, sA, sB);
      halo_write2<2>(h1n, h2n, sxo, cih, sA, sB);
      halo_load2<4>(fbn, y0, x0, sxo, sA, sB);
      halo_write2<4>(h1n, h2n, sxo, cih, sA, sB);
      halo_load2<6>(fbn, y0, x0, sxo, sA, sB);
      halo_write2<6>(h1n, h2n, sxo, cih, sA, sB);
      halo_load2<8>(fbn, y0, x0, sxo, sA, sB);
      halo_write2<8>(h1n, h2n, sxo, cih, sA, sB);
    }
  }

  // ---- preload fb pair for (s=0, j=0) ----
  const ushort_t* pb = p12 + (size_t)zi*1179648 + (size_t)wnb*2048 + lane*8;
  f16x8 nb1 = *(const f16x8*)pb;
  f16x8 nb2 = *(const f16x8*)(pb + 512);

  for (int c = 0; c < 16; ++c) {
    __syncthreads();   // buf[c&1] ready; all reads of buf[(c+1)&1] (iter c-1) done
    const ushort_t* h1c = H1[c & 1];
    const ushort_t* h2c = H2[c & 1];
    u32* h1n = (u32*)H1[(c + 1) & 1];
    u32* h2n = (u32*)H2[(c + 1) & 1];
    const float* fbn = feat + (size_t)(2*cih)*HWP + (size_t)(c + 1)*32*HWP;
    const bool stg = act && (c < 15);

    #pragma unroll 1
    for (int tap = 0; tap < 9; ++tap) {
      const int dy = tap/3, dx = tap - (tap/3)*3;
      // ---- A fragments: 8 ds_read_b128 (linear layout), issued first ----
      f16x8 fa1[4], fa2[4];
      #pragma unroll
      for (int i = 0; i < 4; ++i) {
        int addr = (lyb + i + dy)*(18*CS) + dx*CS + fragoff;
        fa1[i] = *(const f16x8*)&h1c[addr];
        fa2[i] = *(const f16x8*)&h2c[addr];
      }
      // ---- T14 staging: load batch @ tap k, write @ tap k+1 (1 batch live) ----
      if (stg) {
        if (tap == 0) {
          halo_load2<0>(fbn, y0, x0, sxo, sA, sB);
        } else if (tap == 1) {
          halo_write2<0>(h1n, h2n, sxo, cih, sA, sB);
          halo_load2<2>(fbn, y0, x0, sxo, sA, sB);
        } else if (tap == 2) {
          halo_write2<2>(h1n, h2n, sxo, cih, sA, sB);
          halo_load2<4>(fbn, y0, x0, sxo, sA, sB);
        } else if (tap == 3) {
          halo_write2<4>(h1n, h2n, sxo, cih, sA, sB);
          halo_load2<6>(fbn, y0, x0, sxo, sA, sB);
        } else if (tap == 4) {
          halo_write2<6>(h1n, h2n, sxo, cih, sA, sB);
          halo_load2<8>(fbn, y0, x0, sxo, sA, sB);
        } else if (tap == 5) {
          halo_write2<8>(h1n, h2n, sxo, cih, sA, sB);
        }
      }
      // ---- 2 j-stages: {consume prefetched pair; prefetch next; 12 MFMA} ----
      const bool lastS = (c == 15) && (tap == 8);
      const ushort_t* pbn = lastS ? pb : (pb + 8192);
      #pragma unroll
      for (int j = 0; j < 2; ++j) {
        f16x8 cb1 = nb1, cb2 = nb2;
        const ushort_t* nx = (j < 1) ? (pb + 1024) : pbn;
        nb1 = *(const f16x8*)nx;
        nb2 = *(const f16x8*)(nx + 512);
        #pragma unroll
        for (int i = 0; i < 4; ++i) {
          accM[i][j] = __builtin_amdgcn_mfma_f32_16x16x32_f16(fa1[i], cb1, accM[i][j], 0, 0, 0);
          accC[i][j] = __builtin_amdgcn_mfma_f32_16x16x32_f16(fa1[i], cb2, accC[i][j], 0, 0, 0);
          accC[i][j] = __builtin_amdgcn_mfma_f32_16x16x32_f16(fa2[i], cb1, accC[i][j], 0, 0, 0);
        }
      }
      pb = pbn;
    }
  }

  // epilogue: combine main + scaled cross, bias + relu, store x[och][pixel]
  #pragma unroll
  for (int i = 0; i < 4; ++i) {
    int prow = wm + i*16 + lg*4;
    #pragma unroll
    for (int j = 0; j < 2; ++j) {
      int o = ob + wnb*32 + j*16 + lm;
      float bias = b1[o];
      #pragma unroll
      for (int r = 0; r < 4; ++r) {
        int p  = prow + r;
        int yy = y0 + (p >> 4), xx = x0 + (p & 15);
        if (xx < WW) {
          float v = accM[i][j][r] + accC[i][j][r] * 4.8828125e-4f + bias; // 2^-11
          xout[(size_t)o*HWP + yy*200 + xx] = fmaxf(v, 0.f);
        }
      }
    }
  }
}

// ---------------- K2: 1x1 convs (cls+loc) as GEMM [40000 x 64] = x^T[40000x512] * wt[512x64] ----
// R13: 512 threads/block (was 256). Old config: 313 blocks x 4 waves = 1.2 waves/SIMD
// (~4% of wave capacity) -- a latency-bound LDS GEMM with nothing to hide stalls.
// Now 8 waves/block (~2.4/SIMD, ~10 waves/CU). Per thread: 4px x 4och (acc 16).
// Per-output k-order FMA chain unchanged -> bit-identical results.
__global__ __launch_bounds__(512, 2) void conv1x1(const float* __restrict__ x,
                                                  const float* __restrict__ wt,
                                                  const float* __restrict__ bias,
                                                  float* __restrict__ out) {
  __shared__ float Xs[16*128];
  __shared__ float Ws[16*64];
  const int t = threadIdx.x;
  const int m0 = blockIdx.x*128;
  float acc[16];
  #pragma unroll
  for (int i = 0; i < 16; ++i) acc[i] = 0.f;
  const int mb = t & 31, nb = t >> 5;      // 32 m-groups (4px) x 16 n-groups (4och)
  const int mm = t & 127, hh = t >> 7;     // Xs staging: 4 rows/thread
  const int nn = t & 63,  h2 = t >> 6;     // Ws staging: 2 rows/thread

  for (int kb = 0; kb < 512; kb += 16) {
    #pragma unroll
    for (int j = 0; j < 4; ++j) {
      int kk = hh + 4*j;
      Xs[kk*128 + mm] = x[(size_t)(kb+kk)*HWP + m0 + mm];
    }
    #pragma unroll
    for (int j = 0; j < 2; ++j) {
      int kk = h2 + 8*j;
      Ws[kk*64 + nn] = wt[(size_t)(kb+kk)*64 + nn];
    }
    __syncthreads();
    #pragma unroll
    for (int kk = 0; kk < 16; ++kk) {
      float av[4], bv[4];
      *(float4*)&av[0] = *(const float4*)&Xs[kk*128 + mb*4];
      *(float4*)&bv[0] = *(const float4*)&Ws[kk*64 + nb*4];
      #pragma unroll
      for (int i = 0; i < 4; ++i)
        #pragma unroll
        for (int jj = 0; jj < 4; ++jj)
          acc[i*4+jj] = fmaf(av[i], bv[jj], acc[i*4+jj]);
    }
    __syncthreads();
  }

  #pragma unroll
  for (int jj = 0; jj < 4; ++jj) {
    int o = nb*4 + jj;
    float bv = bias[o];
    #pragma unroll
    for (int i = 0; i < 4; ++i) {
      int mm2 = m0 + mb*4 + i;
      if (mm2 < HWP) {
        float v = acc[i*4+jj] + bv;
        if (o < 18)       out[(size_t)mm2*18 + o] = v;               // pred_cls: [m][2a+c]
        else if (o < 54)  out[720000 + (size_t)mm2*36 + (o-18)] = v; // pred_loc: [m][4a+j]
      }
    }
  }
}

// ---------------- K3: decode boxes + score + histogram ----------------
__global__ void decode(const float* __restrict__ dout, const float* __restrict__ anchor,
                       float* __restrict__ scores, float4* __restrict__ roi, u32* __restrict__ hist) {
  int n = blockIdx.x*256 + threadIdx.x;
  if (n >= NANCH) return;
  int mq = n / 9;
  int a  = n - mq*9;
  float2 cv = *(const float2*)(dout + (size_t)mq*18 + 2*a);     // 8B-aligned
  float score = 1.0f / (1.0f + expf(cv.x - cv.y));  // == softmax[:,1]
  float4 lv = *(const float4*)(dout + 720000 + (size_t)mq*36 + 4*a);  // 16B-aligned
  float l0 = lv.x, l1 = lv.y, l2 = lv.z, l3 = lv.w;
  float4 an = ((const float4*)anchor)[n];
  float aw = an.z - an.x, ah = an.w - an.y;
  float acx = (an.x + an.z)*0.5f, acy = (an.y + an.w)*0.5f;
  float cx = l0*aw + acx, cy = l1*ah + acy;
  float bw = expf(l2)*aw, bh = expf(l3)*ah;
  float x1 = fminf(fmaxf(cx - bw*0.5f, 0.f), 1.f);
  float y1 = fminf(fmaxf(cy - bh*0.5f, 0.f), 1.f);
  float x2 = fminf(fmaxf(cx + bw*0.5f, 0.f), 1.f);
  float y2 = fminf(fmaxf(cy + bh*0.5f, 0.f), 1.f);
  bool valid = ((y2 - y1) >= 0.016f) && ((x2 - x1) >= 0.016f);
  float sc = valid ? score : -1.0f;
  scores[n] = sc;
  roi[n] = make_float4(x1, y1, x2, y2);
  atomicAdd(&hist[bucket_of(sc)], 1u);
}

// ---------------- K4: find cutoff bucket B ----------------
__global__ void scan_hist(const u32* __restrict__ hist, u32* __restrict__ ctrl) {
  __shared__ u32 seg[256];
  int t = threadIdx.x;
  u32 s = 0;
  for (int b = 0; b < 64; ++b) s += hist[t*64 + b];
  seg[t] = s;
  __syncthreads();
  if (t == 0) {
    u32 cum = 0; int B = 0;
    for (int sg = 255; sg >= 0; --sg) {
      if (cum + seg[sg] >= PRE) {
        for (int b = sg*64 + 63; b >= sg*64; --b) {
          cum += hist[b];
          if (cum >= PRE) { B = b; break; }
        }
        break;
      }
      cum += seg[sg];
    }
    ctrl[1] = (u32)B;
  }
}

// ---------------- K5: compact candidates (bucket >= B) into keybuf ----------------
__global__ void compact(const float* __restrict__ scores, u32* __restrict__ ctrl, u64* __restrict__ keybuf) {
  int n = blockIdx.x*256 + threadIdx.x;
  if (n >= NANCH) return;
  float s = scores[n];
  int B = (int)ctrl[1];
  if (bucket_of(s) >= B) {
    u32 pos = atomicAdd(&ctrl[0], 1u);
    if (pos < KCAP) {
      keybuf[pos] = ((u64)fsort(s) << 32) | (u64)(0xFFFFFFFFu - (u32)n); // ties: lower n wins
    }
  }
}

// ---------------- K6: single-block bitonic sort of 8192 u64 keys, descending ----------------
__global__ __launch_bounds__(1024) void sortk(const u64* __restrict__ keybuf, const u32* __restrict__ ctrl,
                                              u64* __restrict__ sorted) {
  __shared__ u64 s[KCAP];
  int t = threadIdx.x;
  u32 cnt = ctrl[0]; if (cnt > KCAP) cnt = KCAP;
  for (int i = t; i < KCAP; i += 1024) s[i] = (i < (int)cnt) ? keybuf[i] : 0ULL;
  __syncthreads();
  for (int size = 2; size <= KCAP; size <<= 1) {
    for (int stride = size >> 1; stride > 0; stride >>= 1) {
      for (int w = t; w < KCAP/2; w += 1024) {
        int lo = ((w & ~(stride-1)) << 1) | (w & (stride-1));
        int hi = lo + stride;
        bool desc = ((lo & size) == 0);
        u64 a = s[lo], b = s[hi];
        if ((a < b) == desc) { s[lo] = b; s[hi] = a; }
      }
      __syncthreads();
    }
  }
  for (int i = t; i < 6016; i += 1024) sorted[i] = s[i];
}

// ---------------- K6b: gather top-6000 boxes + validity bits ----------------
__global__ void gather_topk(const u64* __restrict__ sorted, const float4* __restrict__ roi,
                            float4* __restrict__ boxes, u64* __restrict__ validw) {
  int i = blockIdx.x*64 + threadIdx.x;
  bool valid = false;
  float4 b = make_float4(0.f, 0.f, 0.f, 0.f);
  if (i < PRE) {
    u64 k = sorted[i];
    if (k) {
      u32 n = 0xFFFFFFFFu - (u32)(k & 0xFFFFFFFFu);
      if (n < NANCH) { b = roi[n]; valid = (k >> 63) != 0; }
    }
  }
  boxes[i] = b;
  u64 bal = __ballot(valid);
  if (threadIdx.x == 0) validw[blockIdx.x] = bal;
}

// ---------------- K7: NMS suppression bitmask ----------------
__global__ void nms_mask(const float4* __restrict__ boxes, u64* __restrict__ mask) {
  int bi = blockIdx.y, bj = blockIdx.x;
  int t = threadIdx.x;
  int i = bi*64 + t;
  if (bj < bi) {
    if (i < PRE) mask[(size_t)i*NW + bj] = 0ULL;
    return;
  }
  __shared__ float4 cb[64];
  int j0 = bj*64;
  cb[t] = boxes[j0 + t];
  __syncthreads();
  if (i >= PRE) return;
  float4 b = boxes[i];
  float area_i = (b.z - b.x) * (b.w - b.y);
  u64 bits = 0;
  #pragma unroll 4
  for (int jj = 0; jj < 64; ++jj) {
    int j = j0 + jj;
    float4 c = cb[jj];
    float xx1 = fmaxf(b.x, c.x), yy1 = fmaxf(b.y, c.y);
    float xx2 = fminf(b.z, c.z), yy2 = fminf(b.w, c.w);
    float inter = fmaxf(xx2 - xx1, 0.f) * fmaxf(yy2 - yy1, 0.f);
    float area_j = (c.z - c.x) * (c.w - c.y);
    float iou = inter / (area_i + area_j - inter + 1e-12f);
    if (iou > 0.7f && j > i) bits |= (1ULL << jj);
  }
  mask[(size_t)i*NW + bj] = bits;
}

// ---------------- K8: sequential greedy scan, 8-deep mask-row prefetch ring ----------------
// (R12: neutral vs 1-deep; kept -- no cost, slightly safer pipelining.)
__global__ void nms_scan(const u64* __restrict__ mask, const u64* __restrict__ validw,
                         const float* __restrict__ boxes, float* __restrict__ rois) {
  int lane = threadIdx.x;
  const bool hi = lane < NW-64;
  u64 r0 = ~validw[lane];
  u64 r1 = hi ? ~validw[64 + lane] : ~0ULL;
  int kept = 0;
  u64 a0,a1,b0,b1,c0,c1,d0,d1,e0,e1,f0,f1,g0,g1,h0,h1;
#define LOADR(S0,S1,ROW) { S0 = mask[(size_t)(ROW)*NW + lane]; S1 = hi ? mask[(size_t)(ROW)*NW + 64 + lane] : 0ULL; }
  LOADR(a0,a1,0) LOADR(b0,b1,1) LOADR(c0,c1,2) LOADR(d0,d1,3)
  LOADR(e0,e1,4) LOADR(f0,f1,5) LOADR(g0,g1,6) LOADR(h0,h1,7)
#define STEP(S0,S1,II) { \
    int wi = (II) >> 6; \
    u64 w0 = __shfl(r0, wi & 63); \
    u64 w1 = __shfl(r1, wi & 63); \
    u64 wv = (wi < 64) ? w0 : w1; \
    if (!((wv >> ((II) & 63)) & 1ULL)) { \
      if (lane < 4) rois[kept*4 + lane] = boxes[(size_t)(II)*4 + lane]; \
      kept++; \
      if (kept >= POST) goto done; \
      r0 |= S0; \
      if (hi) r1 |= S1; \
    } \
    if ((II) + 8 < PRE) LOADR(S0, S1, (II)+8) }
  for (int i = 0; i < PRE; i += 8) {
    STEP(a0,a1,i)   STEP(b0,b1,i+1) STEP(c0,c1,i+2) STEP(d0,d1,i+3)
    STEP(e0,e1,i+4) STEP(f0,f1,i+5) STEP(g0,g1,i+6) STEP(h0,h1,i+7)
  }
done: ;
#undef STEP
#undef LOADR
}

extern "C" void kernel_launch(void* const* d_in, const int* in_sizes, int n_in,
                              void* d_out, int out_size, void* d_ws, size_t ws_size,
                              hipStream_t stream) {
  const float* feat   = (const float*)d_in[0];
  const float* anchor = (const float*)d_in[1];
  const float* w1     = (const float*)d_in[2];
  const float* b1     = (const float*)d_in[3];
  const float* wc     = (const float*)d_in[4];
  const float* bc     = (const float*)d_in[5];
  const float* wl     = (const float*)d_in[6];
  const float* bl     = (const float*)d_in[7];
  float* out = (float*)d_out;
  char*  ws  = (char*)d_ws;
  float* wsf = (float*)d_ws;

  if (ws_size < WS_END) return;  // need ~103.5 MB

  float*    x      = wsf + X_F;
  ushort_t* p12    = (ushort_t*)(wsf + W1B_F);   // packed B planes 1+2 (f16, 9.44 MB)
  float*    wt64   = wsf + WT64_F;
  float*    b64    = wsf + B64_F;
  float*    scores = wsf + SC_F;
  float4*   roi    = (float4*)(wsf + ROI_F);
  float4*   boxes  = (float4*)(wsf + BOX_F);
  u32* hist   = (u32*)(ws + HIST_B);
  u32* ctrl   = (u32*)(ws + CTRL_B);
  u64* keybuf = (u64*)(ws + KEY_B);
  u64* sorted = (u64*)(ws + SORT_B);
  u64* validw = (u64*)(ws + VALW_B);
  u64* mask   = (u64*)(ws + MASK_B);

  hipMemsetAsync(ws + HIST_B, 0, NBINS*4 + 256, stream);
  hipMemsetAsync(out + 2160000, 0, POST*4*sizeof(float), stream);

  pack_w1b<<<9216, 256, 0, stream>>>(w1, p12);
  pack_wcl<<<129, 256, 0, stream>>>(wc, bc, wl, bl, wt64, b64);
  conv3x3_mfma<<<dim3(13, 25, 4), 512, 0, stream>>>(feat, p12, b1, x);
  conv1x1<<<313, 512, 0, stream>>>(x, wt64, b64, out);
  decode<<<1407, 256, 0, stream>>>(out, anchor, scores, roi, hist);
  scan_hist<<<1, 256, 0, stream>>>(hist, ctrl);
  compact<<<1407, 256, 0, stream>>>(scores, ctrl, keybuf);
  sortk<<<1, 1024, 0, stream>>>(keybuf, ctrl, sorted);
  gather_topk<<<NW, 64, 0, stream>>>(sorted, roi, boxes, validw);
  nms_mask<<<dim3(NW, NW), 64, 0, stream>>>(boxes, mask);
  nms_scan<<<1, 64, 0, stream>>>(mask, validw, (const float*)boxes, out + 2160000);
}

// Round 14
// 1237.882 us; speedup vs baseline: 1.9278x; 1.0007x over previous
//
#include <hip/hip_runtime.h>

typedef unsigned long long u64;
typedef unsigned int u32;
typedef unsigned short ushort_t;

#define HH 200
#define WW 200
#define HWP 40000          // 200*200 pixels
#define NANCH 360000       // HWP * 9
#define PRE 6000
#define POST 300
#define NW 94              // 64-bit mask words per NMS row (ceil(6000/64))
#define NBINS 16384
#define KCAP 8192
#define CS 40              // halo cell stride in ushorts (80B): 16B-aligned

typedef __attribute__((ext_vector_type(8))) _Float16 f16x8;
typedef __attribute__((ext_vector_type(4))) float f32x4;

// ---------------- workspace layout (unchanged footprint) ----
static constexpr size_t X_F    = 0;                          // conv1 output x[512][40000] (+64 slack)
static constexpr size_t X_CNT  = 512ULL*HWP + 64;
static constexpr size_t W1B_F  = X_F + X_CNT;                // packed B planes 1+2 (f16): 4.72M ushorts
static constexpr size_t WT64_F = W1B_F + 4608ULL*512;        // packed cls/loc weights [512][64]
static constexpr size_t B64_F  = WT64_F + 512ULL*64;         // packed bias [64]
static constexpr size_t SC_F   = B64_F + 64;                 // scores [360000]
static constexpr size_t ROI_F  = SC_F + NANCH;               // decoded boxes [360000][4]
static constexpr size_t BOX_F  = ROI_F + 4ULL*NANCH;         // top-6000 boxes (pad 6016) [4]
static constexpr size_t FEND_F = BOX_F + 6016ULL*4;
static constexpr size_t HIST_B = ((FEND_F*4 + 255)/256)*256; // u32[16384]
static constexpr size_t CTRL_B = HIST_B + NBINS*4;           // u32[64]: [0]=cnt, [1]=cutoff bucket
static constexpr size_t KEY_B  = CTRL_B + 256;               // u64[8192] candidate keys
static constexpr size_t SORT_B = KEY_B + (size_t)KCAP*8;     // u64[6016] sorted keys
static constexpr size_t VALW_B = SORT_B + 6016ULL*8;         // u64[94] validity bits
static constexpr size_t MASK_B = ((VALW_B + NW*8 + 255)/256)*256; // u64[6000][94] NMS mask
static constexpr size_t WS_END = MASK_B + (size_t)PRE*NW*8;  // ~103.5 MB total

// ---------------- helpers ----------------
__device__ __forceinline__ u32 fsort(float f) {
  u32 u = __float_as_uint(f);
  return (u & 0x80000000u) ? ~u : (u | 0x80000000u);
}
__device__ __forceinline__ int bucket_of(float s) {
  int b = (int)((s + 1.0f) * 8191.0f);
  return b < 0 ? 0 : (b > 16383 ? 16383 : b);
}
__device__ __forceinline__ ushort_t h_bits(_Float16 h) {
  union { _Float16 h; ushort_t u; } c; c.h = h; return c.u;
}
// f16x2 split of a float pair -> two packed u32 (plane1: h1, plane2: h2*2048)
__device__ __forceinline__ void split_pack(float fA, float fB, u32& w1, u32& w2) {
  _Float16 hA = (_Float16)fA, hB = (_Float16)fB;
  float rA = fA - (float)hA, rB = fB - (float)hB;
  _Float16 cA = (_Float16)(rA * 2048.0f), cB = (_Float16)(rB * 2048.0f);
  w1 = (u32)h_bits(hA) | ((u32)h_bits(hB) << 16);
  w2 = (u32)h_bits(cA) | ((u32)h_bits(cB) << 16);
}

// single-x halo load (one ci-pair): raw floats, no split
__device__ __forceinline__ void halo_load1(const float* __restrict__ fbn, int y, int y0, int x0,
                                           int x, float& a0, float& b0) {
  int gy = y0 + y - 1, gx = x0 + x - 1;
  bool ok = ((unsigned)gy < 200u) && ((unsigned)gx < 200u);
  int off = ok ? (gy*200 + gx) : 0;
  float fA = fbn[off], fB = fbn[off + HWP];
  a0 = ok ? fA : 0.f;  b0 = ok ? fB : 0.f;
}
// linear write (NO swizzle -- R8 measured: XOR swizzle RAISED conflicts 1.8x)
__device__ __forceinline__ void halo_write1(u32* __restrict__ H1u, u32* __restrict__ H2u,
                                            int y, int x, int cih, float a0, float b0) {
  u32 w1v, w2v;
  split_pack(a0, b0, w1v, w2v);
  int idx = (y*18 + x)*(CS/2) + cih;
  H1u[idx] = w1v;
  H2u[idx] = w2v;
}
// 2-row batches: only 4 floats live per batch per thread
template<int Y0>
__device__ __forceinline__ void halo_load2(const float* __restrict__ fbn, int y0, int x0,
                                           int x, float* sA, float* sB) {
  #pragma unroll
  for (int yy = 0; yy < 2; ++yy)
    halo_load1(fbn, Y0 + yy, y0, x0, x, sA[yy], sB[yy]);
}
template<int Y0>
__device__ __forceinline__ void halo_write2(u32* __restrict__ H1u, u32* __restrict__ H2u,
                                            int x, int cih, float* sA, float* sB) {
  #pragma unroll
  for (int yy = 0; yy < 2; ++yy)
    halo_write1(H1u, H2u, Y0 + yy, x, cih, sA[yy], sB[yy]);
}

// ---------------- K0a: prepack w1 -> 2 f16 planes (h1, h2*2048), TAP-MAJOR k-order ----
// R14: CONTIGUOUS-WRITE restructure. The old mapping (1 thread = 1 (och,k) element)
// issued two SCATTERED 2-byte stores per thread: consecutive threads differ in tap ->
// destinations 16KB apart, so every u16 store dirtied its own 32B HBM sector
// (~300MB effective writes for 18.9MB useful). New mapping: 1 thread = 1 fragment run
// (och, s, lg) -> computes e=0..7 and emits TWO 16B dwordx4 stores (plane1, plane2).
// Reads: w1[och*4608 + ci*9 + tap], ci = chunk*32+lg*8+e (stride 36B); one wave's
// taps 0..8 of a chunk jointly cover a contiguous 1152B span -> L1-absorbed.
// Values and destination addresses identical to R6's pack -> BIT-IDENTICAL buffer.
// Layout (R6 grouping, verified): base = ((z*144+s)*4+wnb)*2+j; addr = base*1024
// + p*512 + lane*8 + e; z=och>>7, oz=och&127, wnb=oz>>5, j=(oz>>4)&1, lane=lg*16+(oz&15).
__global__ void pack_w1b(const float* __restrict__ w1, ushort_t* __restrict__ p12) {
  int u = blockIdx.x*256 + threadIdx.x;
  if (u >= 512*576) return;                 // 512 och x 144 s x 4 lg
  int och = u / 576, rem = u - och*576;
  int s = rem >> 2, lg = rem & 3;
  int chunk = s / 9, tap = s - chunk*9;
  const float* wp = w1 + (size_t)och*4608 + (size_t)(chunk*32 + lg*8)*9 + tap;

  ushort_t o1[8], o2[8];
  #pragma unroll
  for (int e = 0; e < 8; ++e) {
    float f = wp[e*9];
    _Float16 h1 = (_Float16)f;
    float r = f - (float)h1;
    _Float16 h2 = (_Float16)(r * 2048.0f);
    o1[e] = h_bits(h1);
    o2[e] = h_bits(h2);
  }

  int z = och >> 7, oz = och & 127;
  int wnb = oz >> 5, j = (oz >> 4) & 1, lmm = oz & 15;
  int lane = lg*16 + lmm;
  size_t base = (((size_t)z*144 + s)*4 + wnb)*2 + j;
  *(uint4*)&p12[base*1024 +       lane*8] = *(const uint4*)o1;
  *(uint4*)&p12[base*1024 + 512 + lane*8] = *(const uint4*)o2;
}

// ---------------- K0b: pack wc(18)/wl(36) -> wt[ci][64] (zero-padded), bias[64] ----------------
__global__ void pack_wcl(const float* __restrict__ wc, const float* __restrict__ bc,
                         const float* __restrict__ wl, const float* __restrict__ bl,
                         float* __restrict__ wt, float* __restrict__ b64) {
  int idx = blockIdx.x*256 + threadIdx.x;
  if (idx < 512*64) {
    int ci = idx >> 6, o = idx & 63;
    float v = 0.f;
    if (o < 18) v = wc[o*512 + ci];
    else if (o < 54) v = wl[(o-18)*512 + ci];
    wt[idx] = v;
  } else if (idx < 512*64 + 64) {
    int o = idx - 512*64;
    float v = 0.f;
    if (o < 18) v = bc[o]; else if (o < 54) v = bl[o-18];
    b64[o] = v;
  }
}

// ---------------- K1: 3x3 conv 512->512 + ReLU, f16x2 split, halo-LDS tap-major ----------
// R14 = R6 VERBATIM (best verified: conv 747-753us; R7-R11 all regressed; frozen).
__global__ __launch_bounds__(512, 2) void conv3x3_mfma(const float* __restrict__ feat,
    const ushort_t* __restrict__ p12,
    const float* __restrict__ b1, float* __restrict__ xout) {
  __shared__ ushort_t H1[2][10*18*CS], H2[2][10*18*CS];   // double-buffered halo, 57.6KB
  const int t = threadIdx.x;
  const int x0 = blockIdx.x*16, y0 = blockIdx.y*8;
  const int zi = blockIdx.z;
  const int ob = zi*128;

  const int wave = t >> 6, lane = t & 63;
  const int wm = (wave & 1)*64;            // M half (64 pixels)
  const int wnb = wave >> 1;               // N quarter (32 och)
  const int lm = lane & 15, lg = lane >> 4;
  const int lyb = (wave & 1)*4;            // tile-row base of this wave's M
  const int fragoff = lm*CS + lg*8;        // per-lane ushort offset into a halo row

  // staging map: cih = t>>5 (ci pair 0..15), x-slot = t&31 (active if <18)
  const int cih = t >> 5;
  const int sxo = t & 31;
  const bool act = sxo < 18;

  f32x4 accM[4][2], accC[4][2];
  #pragma unroll
  for (int i = 0; i < 4; ++i)
    #pragma unroll
    for (int j = 0; j < 2; ++j) {
      accM[i][j] = (f32x4){0.f, 0.f, 0.f, 0.f};
      accC[i][j] = (f32x4){0.f, 0.f, 0.f, 0.f};
    }

  float sA[2], sB[2];                      // one 2-row staging batch (4 floats)

  // ---- prologue: stage chunk 0 into buffer 0 (5 sequential 2-row batches) ----
  {
    const float* fbn = feat + (size_t)(2*cih)*HWP;
    u32* h1n = (u32*)H1[0];  u32* h2n = (u32*)H2[0];
    if (act) {
      halo_load2<0>(fbn, y0, x0, sxo, sA, sB);
      halo_write2<0>(h1n, h2n, sxo, cih, sA, sB);
      halo_load2<2>(fbn, y0, x0, sxo, sA, sB);
      halo_write2<2>(h1n, h2n, sxo, cih, sA, sB);
      halo_load2<4>(fbn, y0, x0, sxo, sA, sB);
      halo_write2<4>(h1n, h2n, sxo, cih, sA, sB);
      halo_load2<6>(fbn, y0, x0, sxo, sA, sB);
      halo_write2<6>(h1n, h2n, sxo, cih, sA, sB);
      halo_load2<8>(fbn, y0, x0, sxo, sA, sB);
      halo_write2<8>(h1n, h2n, sxo, cih, sA, sB);
    }
  }

  // ---- preload fb pair for (s=0, j=0) ----
  const ushort_t* pb = p12 + (size_t)zi*1179648 + (size_t)wnb*2048 + lane*8;
  f16x8 nb1 = *(const f16x8*)pb;
  f16x8 nb2 = *(const f16x8*)(pb + 512);

  for (int c = 0; c < 16; ++c) {
    __syncthreads();   // buf[c&1] ready; all reads of buf[(c+1)&1] (iter c-1) done
    const ushort_t* h1c = H1[c & 1];
    const ushort_t* h2c = H2[c & 1];
    u32* h1n = (u32*)H1[(c + 1) & 1];
    u32* h2n = (u32*)H2[(c + 1) & 1];
    const float* fbn = feat + (size_t)(2*cih)*HWP + (size_t)(c + 1)*32*HWP;
    const bool stg = act && (c < 15);

    #pragma unroll 1
    for (int tap = 0; tap < 9; ++tap) {
      const int dy = tap/3, dx = tap - (tap/3)*3;
      // ---- A fragments: 8 ds_read_b128 (linear layout), issued first ----
      f16x8 fa1[4], fa2[4];
      #pragma unroll
      for (int i = 0; i < 4; ++i) {
        int addr = (lyb + i + dy)*(18*CS) + dx*CS + fragoff;
        fa1[i] = *(const f16x8*)&h1c[addr];
        fa2[i] = *(const f16x8*)&h2c[addr];
      }
      // ---- T14 staging: load batch @ tap k, write @ tap k+1 (1 batch live) ----
      if (stg) {
        if (tap == 0) {
          halo_load2<0>(fbn, y0, x0, sxo, sA, sB);
        } else if (tap == 1) {
          halo_write2<0>(h1n, h2n, sxo, cih, sA, sB);
          halo_load2<2>(fbn, y0, x0, sxo, sA, sB);
        } else if (tap == 2) {
          halo_write2<2>(h1n, h2n, sxo, cih, sA, sB);
          halo_load2<4>(fbn, y0, x0, sxo, sA, sB);
        } else if (tap == 3) {
          halo_write2<4>(h1n, h2n, sxo, cih, sA, sB);
          halo_load2<6>(fbn, y0, x0, sxo, sA, sB);
        } else if (tap == 4) {
          halo_write2<6>(h1n, h2n, sxo, cih, sA, sB);
          halo_load2<8>(fbn, y0, x0, sxo, sA, sB);
        } else if (tap == 5) {
          halo_write2<8>(h1n, h2n, sxo, cih, sA, sB);
        }
      }
      // ---- 2 j-stages: {consume prefetched pair; prefetch next; 12 MFMA} ----
      const bool lastS = (c == 15) && (tap == 8);
      const ushort_t* pbn = lastS ? pb : (pb + 8192);
      #pragma unroll
      for (int j = 0; j < 2; ++j) {
        f16x8 cb1 = nb1, cb2 = nb2;
        const ushort_t* nx = (j < 1) ? (pb + 1024) : pbn;
        nb1 = *(const f16x8*)nx;
        nb2 = *(const f16x8*)(nx + 512);
        #pragma unroll
        for (int i = 0; i < 4; ++i) {
          accM[i][j] = __builtin_amdgcn_mfma_f32_16x16x32_f16(fa1[i], cb1, accM[i][j], 0, 0, 0);
          accC[i][j] = __builtin_amdgcn_mfma_f32_16x16x32_f16(fa1[i], cb2, accC[i][j], 0, 0, 0);
          accC[i][j] = __builtin_amdgcn_mfma_f32_16x16x32_f16(fa2[i], cb1, accC[i][j], 0, 0, 0);
        }
      }
      pb = pbn;
    }
  }

  // epilogue: combine main + scaled cross, bias + relu, store x[och][pixel]
  #pragma unroll
  for (int i = 0; i < 4; ++i) {
    int prow = wm + i*16 + lg*4;
    #pragma unroll
    for (int j = 0; j < 2; ++j) {
      int o = ob + wnb*32 + j*16 + lm;
      float bias = b1[o];
      #pragma unroll
      for (int r = 0; r < 4; ++r) {
        int p  = prow + r;
        int yy = y0 + (p >> 4), xx = x0 + (p & 15);
        if (xx < WW) {
          float v = accM[i][j][r] + accC[i][j][r] * 4.8828125e-4f + bias; // 2^-11
          xout[(size_t)o*HWP + yy*200 + xx] = fmaxf(v, 0.f);
        }
      }
    }
  }
}

// ---------------- K2: 1x1 convs (cls+loc) as GEMM [40000 x 64] = x^T[40000x512] * wt[512x64] ----
// R13 config (kept): 512 threads/block, 4px x 4och per thread, bit-identical k-order.
__global__ __launch_bounds__(512, 2) void conv1x1(const float* __restrict__ x,
                                                  const float* __restrict__ wt,
                                                  const float* __restrict__ bias,
                                                  float* __restrict__ out) {
  __shared__ float Xs[16*128];
  __shared__ float Ws[16*64];
  const int t = threadIdx.x;
  const int m0 = blockIdx.x*128;
  float acc[16];
  #pragma unroll
  for (int i = 0; i < 16; ++i) acc[i] = 0.f;
  const int mb = t & 31, nb = t >> 5;      // 32 m-groups (4px) x 16 n-groups (4och)
  const int mm = t & 127, hh = t >> 7;     // Xs staging: 4 rows/thread
  const int nn = t & 63,  h2 = t >> 6;     // Ws staging: 2 rows/thread

  for (int kb = 0; kb < 512; kb += 16) {
    #pragma unroll
    for (int j = 0; j < 4; ++j) {
      int kk = hh + 4*j;
      Xs[kk*128 + mm] = x[(size_t)(kb+kk)*HWP + m0 + mm];
    }
    #pragma unroll
    for (int j = 0; j < 2; ++j) {
      int kk = h2 + 8*j;
      Ws[kk*64 + nn] = wt[(size_t)(kb+kk)*64 + nn];
    }
    __syncthreads();
    #pragma unroll
    for (int kk = 0; kk < 16; ++kk) {
      float av[4], bv[4];
      *(float4*)&av[0] = *(const float4*)&Xs[kk*128 + mb*4];
      *(float4*)&bv[0] = *(const float4*)&Ws[kk*64 + nb*4];
      #pragma unroll
      for (int i = 0; i < 4; ++i)
        #pragma unroll
        for (int jj = 0; jj < 4; ++jj)
          acc[i*4+jj] = fmaf(av[i], bv[jj], acc[i*4+jj]);
    }
    __syncthreads();
  }

  #pragma unroll
  for (int jj = 0; jj < 4; ++jj) {
    int o = nb*4 + jj;
    float bv = bias[o];
    #pragma unroll
    for (int i = 0; i < 4; ++i) {
      int mm2 = m0 + mb*4 + i;
      if (mm2 < HWP) {
        float v = acc[i*4+jj] + bv;
        if (o < 18)       out[(size_t)mm2*18 + o] = v;               // pred_cls: [m][2a+c]
        else if (o < 54)  out[720000 + (size_t)mm2*36 + (o-18)] = v; // pred_loc: [m][4a+j]
      }
    }
  }
}

// ---------------- K3: decode boxes + score + histogram ----------------
__global__ void decode(const float* __restrict__ dout, const float* __restrict__ anchor,
                       float* __restrict__ scores, float4* __restrict__ roi, u32* __restrict__ hist) {
  int n = blockIdx.x*256 + threadIdx.x;
  if (n >= NANCH) return;
  int mq = n / 9;
  int a  = n - mq*9;
  float2 cv = *(const float2*)(dout + (size_t)mq*18 + 2*a);     // 8B-aligned
  float score = 1.0f / (1.0f + expf(cv.x - cv.y));  // == softmax[:,1]
  float4 lv = *(const float4*)(dout + 720000 + (size_t)mq*36 + 4*a);  // 16B-aligned
  float l0 = lv.x, l1 = lv.y, l2 = lv.z, l3 = lv.w;
  float4 an = ((const float4*)anchor)[n];
  float aw = an.z - an.x, ah = an.w - an.y;
  float acx = (an.x + an.z)*0.5f, acy = (an.y + an.w)*0.5f;
  float cx = l0*aw + acx, cy = l1*ah + acy;
  float bw = expf(l2)*aw, bh = expf(l3)*ah;
  float x1 = fminf(fmaxf(cx - bw*0.5f, 0.f), 1.f);
  float y1 = fminf(fmaxf(cy - bh*0.5f, 0.f), 1.f);
  float x2 = fminf(fmaxf(cx + bw*0.5f, 0.f), 1.f);
  float y2 = fminf(fmaxf(cy + bh*0.5f, 0.f), 1.f);
  bool valid = ((y2 - y1) >= 0.016f) && ((x2 - x1) >= 0.016f);
  float sc = valid ? score : -1.0f;
  scores[n] = sc;
  roi[n] = make_float4(x1, y1, x2, y2);
  atomicAdd(&hist[bucket_of(sc)], 1u);
}

// ---------------- K4: find cutoff bucket B ----------------
__global__ void scan_hist(const u32* __restrict__ hist, u32* __restrict__ ctrl) {
  __shared__ u32 seg[256];
  int t = threadIdx.x;
  u32 s = 0;
  for (int b = 0; b < 64; ++b) s += hist[t*64 + b];
  seg[t] = s;
  __syncthreads();
  if (t == 0) {
    u32 cum = 0; int B = 0;
    for (int sg = 255; sg >= 0; --sg) {
      if (cum + seg[sg] >= PRE) {
        for (int b = sg*64 + 63; b >= sg*64; --b) {
          cum += hist[b];
          if (cum >= PRE) { B = b; break; }
        }
        break;
      }
      cum += seg[sg];
    }
    ctrl[1] = (u32)B;
  }
}

// ---------------- K5: compact candidates (bucket >= B) into keybuf ----------------
__global__ void compact(const float* __restrict__ scores, u32* __restrict__ ctrl, u64* __restrict__ keybuf) {
  int n = blockIdx.x*256 + threadIdx.x;
  if (n >= NANCH) return;
  float s = scores[n];
  int B = (int)ctrl[1];
  if (bucket_of(s) >= B) {
    u32 pos = atomicAdd(&ctrl[0], 1u);
    if (pos < KCAP) {
      keybuf[pos] = ((u64)fsort(s) << 32) | (u64)(0xFFFFFFFFu - (u32)n); // ties: lower n wins
    }
  }
}

// ---------------- K6: single-block bitonic sort of 8192 u64 keys, descending ----------------
__global__ __launch_bounds__(1024) void sortk(const u64* __restrict__ keybuf, const u32* __restrict__ ctrl,
                                              u64* __restrict__ sorted) {
  __shared__ u64 s[KCAP];
  int t = threadIdx.x;
  u32 cnt = ctrl[0]; if (cnt > KCAP) cnt = KCAP;
  for (int i = t; i < KCAP; i += 1024) s[i] = (i < (int)cnt) ? keybuf[i] : 0ULL;
  __syncthreads();
  for (int size = 2; size <= KCAP; size <<= 1) {
    for (int stride = size >> 1; stride > 0; stride >>= 1) {
      for (int w = t; w < KCAP/2; w += 1024) {
        int lo = ((w & ~(stride-1)) << 1) | (w & (stride-1));
        int hi = lo + stride;
        bool desc = ((lo & size) == 0);
        u64 a = s[lo], b = s[hi];
        if ((a < b) == desc) { s[lo] = b; s[hi] = a; }
      }
      __syncthreads();
    }
  }
  for (int i = t; i < 6016; i += 1024) sorted[i] = s[i];
}

// ---------------- K6b: gather top-6000 boxes + validity bits ----------------
__global__ void gather_topk(const u64* __restrict__ sorted, const float4* __restrict__ roi,
                            float4* __restrict__ boxes, u64* __restrict__ validw) {
  int i = blockIdx.x*64 + threadIdx.x;
  bool valid = false;
  float4 b = make_float4(0.f, 0.f, 0.f, 0.f);
  if (i < PRE) {
    u64 k = sorted[i];
    if (k) {
      u32 n = 0xFFFFFFFFu - (u32)(k & 0xFFFFFFFFu);
      if (n < NANCH) { b = roi[n]; valid = (k >> 63) != 0; }
    }
  }
  boxes[i] = b;
  u64 bal = __ballot(valid);
  if (threadIdx.x == 0) validw[blockIdx.x] = bal;
}

// ---------------- K7: NMS suppression bitmask ----------------
__global__ void nms_mask(const float4* __restrict__ boxes, u64* __restrict__ mask) {
  int bi = blockIdx.y, bj = blockIdx.x;
  int t = threadIdx.x;
  int i = bi*64 + t;
  if (bj < bi) {
    if (i < PRE) mask[(size_t)i*NW + bj] = 0ULL;
    return;
  }
  __shared__ float4 cb[64];
  int j0 = bj*64;
  cb[t] = boxes[j0 + t];
  __syncthreads();
  if (i >= PRE) return;
  float4 b = boxes[i];
  float area_i = (b.z - b.x) * (b.w - b.y);
  u64 bits = 0;
  #pragma unroll 4
  for (int jj = 0; jj < 64; ++jj) {
    int j = j0 + jj;
    float4 c = cb[jj];
    float xx1 = fmaxf(b.x, c.x), yy1 = fmaxf(b.y, c.y);
    float xx2 = fminf(b.z, c.z), yy2 = fminf(b.w, c.w);
    float inter = fmaxf(xx2 - xx1, 0.f) * fmaxf(yy2 - yy1, 0.f);
    float area_j = (c.z - c.x) * (c.w - c.y);
    float iou = inter / (area_i + area_j - inter + 1e-12f);
    if (iou > 0.7f && j > i) bits |= (1ULL << jj);
  }
  mask[(size_t)i*NW + bj] = bits;
}

// ---------------- K8: sequential greedy scan, 8-deep mask-row prefetch ring ----------------
__global__ void nms_scan(const u64* __restrict__ mask, const u64* __restrict__ validw,
                         const float* __restrict__ boxes, float* __restrict__ rois) {
  int lane = threadIdx.x;
  const bool hi = lane < NW-64;
  u64 r0 = ~validw[lane];
  u64 r1 = hi ? ~validw[64 + lane] : ~0ULL;
  int kept = 0;
  u64 a0,a1,b0,b1,c0,c1,d0,d1,e0,e1,f0,f1,g0,g1,h0,h1;
#define LOADR(S0,S1,ROW) { S0 = mask[(size_t)(ROW)*NW + lane]; S1 = hi ? mask[(size_t)(ROW)*NW + 64 + lane] : 0ULL; }
  LOADR(a0,a1,0) LOADR(b0,b1,1) LOADR(c0,c1,2) LOADR(d0,d1,3)
  LOADR(e0,e1,4) LOADR(f0,f1,5) LOADR(g0,g1,6) LOADR(h0,h1,7)
#define STEP(S0,S1,II) { \
    int wi = (II) >> 6; \
    u64 w0 = __shfl(r0, wi & 63); \
    u64 w1 = __shfl(r1, wi & 63); \
    u64 wv = (wi < 64) ? w0 : w1; \
    if (!((wv >> ((II) & 63)) & 1ULL)) { \
      if (lane < 4) rois[kept*4 + lane] = boxes[(size_t)(II)*4 + lane]; \
      kept++; \
      if (kept >= POST) goto done; \
      r0 |= S0; \
      if (hi) r1 |= S1; \
    } \
    if ((II) + 8 < PRE) LOADR(S0, S1, (II)+8) }
  for (int i = 0; i < PRE; i += 8) {
    STEP(a0,a1,i)   STEP(b0,b1,i+1) STEP(c0,c1,i+2) STEP(d0,d1,i+3)
    STEP(e0,e1,i+4) STEP(f0,f1,i+5) STEP(g0,g1,i+6) STEP(h0,h1,i+7)
  }
done: ;
#undef STEP
#undef LOADR
}

extern "C" void kernel_launch(void* const* d_in, const int* in_sizes, int n_in,
                              void* d_out, int out_size, void* d_ws, size_t ws_size,
                              hipStream_t stream) {
  const float* feat   = (const float*)d_in[0];
  const float* anchor = (const float*)d_in[1];
  const float* w1     = (const float*)d_in[2];
  const float* b1     = (const float*)d_in[3];
  const float* wc     = (const float*)d_in[4];
  const float* bc     = (const float*)d_in[5];
  const float* wl     = (const float*)d_in[6];
  const float* bl     = (const float*)d_in[7];
  float* out = (float*)d_out;
  char*  ws  = (char*)d_ws;
  float* wsf = (float*)d_ws;

  if (ws_size < WS_END) return;  // need ~103.5 MB

  float*    x      = wsf + X_F;
  ushort_t* p12    = (ushort_t*)(wsf + W1B_F);   // packed B planes 1+2 (f16, 9.44 MB)
  float*    wt64   = wsf + WT64_F;
  float*    b64    = wsf + B64_F;
  float*    scores = wsf + SC_F;
  float4*   roi    = (float4*)(wsf + ROI_F);
  float4*   boxes  = (float4*)(wsf + BOX_F);
  u32* hist   = (u32*)(ws + HIST_B);
  u32* ctrl   = (u32*)(ws + CTRL_B);
  u64* keybuf = (u64*)(ws + KEY_B);
  u64* sorted = (u64*)(ws + SORT_B);
  u64* validw = (u64*)(ws + VALW_B);
  u64* mask   = (u64*)(ws + MASK_B);

  hipMemsetAsync(ws + HIST_B, 0, NBINS*4 + 256, stream);
  hipMemsetAsync(out + 2160000, 0, POST*4*sizeof(float), stream);

  pack_w1b<<<1152, 256, 0, stream>>>(w1, p12);
  pack_wcl<<<129, 256, 0, stream>>>(wc, bc, wl, bl, wt64, b64);
  conv3x3_mfma<<<dim3(13, 25, 4), 512, 0, stream>>>(feat, p12, b1, x);
  conv1x1<<<313, 512, 0, stream>>>(x, wt64, b64, out);
  decode<<<1407, 256, 0, stream>>>(out, anchor, scores, roi, hist);
  scan_hist<<<1, 256, 0, stream>>>(hist, ctrl);
  compact<<<1407, 256, 0, stream>>>(scores, ctrl, keybuf);
  sortk<<<1, 1024, 0, stream>>>(keybuf, ctrl, sorted);
  gather_topk<<<NW, 64, 0, stream>>>(sorted, roi, boxes, validw);
  nms_mask<<<dim3(NW, NW), 64, 0, stream>>>(boxes, mask);
  nms_scan<<<1, 64, 0, stream>>>(mask, validw, (const float*)boxes, out + 2160000);
}